// Round 2
// baseline (2230.077 us; speedup 1.0000x reference)
//
#include <hip/hip_runtime.h>

// Problem constants (fixed by setup_inputs)
constexpr int B_ = 16, L_ = 2048, C_ = 256, K_ = 64, INNER_ = 4096;
constexpr int NCH = 16;          // L-chunks for mu partials
constexpr int RPB = L_ / NCH;    // 128 rows per k_em block
constexpr int ICH = 32;          // i-chunk for k_mlp
#define EPSF 1e-6f

typedef __attribute__((ext_vector_type(8))) short bf16x8;
typedef __attribute__((ext_vector_type(4))) float f32x4;

__device__ __forceinline__ unsigned short f2bf(float f) {
  union { float f; unsigned u; } v; v.f = f;
  unsigned r = v.u + 0x7fffu + ((v.u >> 16) & 1u);   // RNE
  return (unsigned short)(r >> 16);
}

// ---------------------------------------------------------------- k_pre
__global__ __launch_bounds__(256) void k_pre(
    const float* __restrict__ w1, const float* __restrict__ w2,
    const float* __restrict__ gamma, const float* __restrict__ beta,
    const float* __restrict__ bmean, const float* __restrict__ bvar,
    const float* __restrict__ b1, const float* __restrict__ mu0,
    unsigned short* __restrict__ w1bf, unsigned short* __restrict__ w2bf,
    float* __restrict__ bnsc, float* __restrict__ bnsh, float* __restrict__ muB)
{
  int i = blockIdx.x * 256 + threadIdx.x;        // grid covers 1048576
  if (i < INNER_ * C_) {
    w1bf[i] = f2bf(w1[i]);
    w2bf[i] = f2bf(w2[i]);
  }
  if (i < K_ * C_ * B_) muB[i] = mu0[i & (K_ * C_ - 1)];
  if (i < INNER_) {
    float s = gamma[i] * rsqrtf(bvar[i] + 1e-5f);
    bnsc[i] = s;
    bnsh[i] = fmaf(b1[i] - bmean[i], s, beta[i]);  // absorbs b1
  }
}

// ---------------------------------------------------------------- k_xT
__global__ __launch_bounds__(256) void k_xT(const float* __restrict__ x, float* __restrict__ xT)
{
  __shared__ float ts[64][65];
  int l0 = blockIdx.x * 64, c0 = blockIdx.y * 64, b = blockIdx.z;
  int t = threadIdx.x;
  for (int p = 0; p < 16; ++p) {
    int e = t + p * 256; int i = e >> 6, j = e & 63;
    ts[i][j] = x[((size_t)b * L_ + l0 + i) * C_ + c0 + j];
  }
  __syncthreads();
  for (int p = 0; p < 16; ++p) {
    int e = t + p * 256; int i2 = e >> 6, j2 = e & 63;
    xT[((size_t)b * C_ + c0 + i2) * L_ + l0 + j2] = ts[j2][i2];
  }
}

// ---------------------------------------------------------------- k_em
// logits (scalar-pipe mu) -> softmax -> z ; colsum ; mu-update partials
template<bool DO_MU>
__global__ __launch_bounds__(256) void k_em(
    const float* __restrict__ xT,   // [B][C][L]
    const float* __restrict__ x,    // [B][L][C]
    const float* __restrict__ mu,   // [B][K][C]
    float* __restrict__ zout,       // [B][L][K]
    float* __restrict__ cp,         // [NCH][B*K]
    float* __restrict__ part)       // [NCH][B][K][C]
{
  __shared__ float z_s[RPB][K_ + 4];     // 34.8KB
  __shared__ float red[2][RPB];
  __shared__ float cpart[4][K_];

  int t = threadIdx.x;
  int b = blockIdx.y;
  int l0 = blockIdx.x * RPB;
  int r = t & (RPB - 1);
  int kh = __builtin_amdgcn_readfirstlane(t >> 7);   // wave-uniform -> scalar mu loads

  // mu pointer is uniform (blockIdx + readfirstlane) -> s_load path
  const float4* muK = (const float4*)(mu + ((size_t)b * K_ + kh * 32) * C_);

  // ---- logits: 32 dots over C; x from xT (coalesced), mu via scalar loads
  float acc[32];
#pragma unroll
  for (int i = 0; i < 32; ++i) acc[i] = 0.f;
  const float* xTb = xT + (size_t)b * C_ * L_ + l0 + r;
  for (int c16 = 0; c16 < C_ / 16; ++c16) {
    float xv[16];
#pragma unroll
    for (int j = 0; j < 16; ++j) xv[j] = xTb[(size_t)(c16 * 16 + j) * L_];
#pragma unroll
    for (int kk = 0; kk < 32; ++kk) {
      const float4* mrow = muK + (size_t)kk * (C_ / 4) + c16 * 4;
      float4 ma = mrow[0], mb = mrow[1], mc = mrow[2], md = mrow[3];
      float a = acc[kk];
      a = fmaf(ma.x, xv[0], a);  a = fmaf(ma.y, xv[1], a);
      a = fmaf(ma.z, xv[2], a);  a = fmaf(ma.w, xv[3], a);
      a = fmaf(mb.x, xv[4], a);  a = fmaf(mb.y, xv[5], a);
      a = fmaf(mb.z, xv[6], a);  a = fmaf(mb.w, xv[7], a);
      a = fmaf(mc.x, xv[8], a);  a = fmaf(mc.y, xv[9], a);
      a = fmaf(mc.z, xv[10], a); a = fmaf(mc.w, xv[11], a);
      a = fmaf(md.x, xv[12], a); a = fmaf(md.y, xv[13], a);
      a = fmaf(md.z, xv[14], a); a = fmaf(md.w, xv[15], a);
      acc[kk] = a;
    }
  }

  // ---- softmax over K=64 via 2-half LDS exchange
  float mx = acc[0];
#pragma unroll
  for (int i = 1; i < 32; ++i) mx = fmaxf(mx, acc[i]);
  red[kh][r] = mx;
  __syncthreads();
  float m = fmaxf(red[0][r], red[1][r]);
  float s = 0.f;
#pragma unroll
  for (int i = 0; i < 32; ++i) { acc[i] = __expf(acc[i] - m); s += acc[i]; }
  __syncthreads();
  red[kh][r] = s;
  __syncthreads();
  float inv = 1.f / (red[0][r] + red[1][r]);
#pragma unroll
  for (int i = 0; i < 32; ++i) acc[i] *= inv;

  // write z to LDS + global
  float* zo = zout + ((size_t)b * L_ + l0 + r) * K_ + kh * 32;
#pragma unroll
  for (int i = 0; i < 32; i += 4) {
    float4 v = make_float4(acc[i], acc[i + 1], acc[i + 2], acc[i + 3]);
    *(float4*)(&z_s[r][kh * 32 + i]) = v;
    *(float4*)(zo + i) = v;
  }
  __syncthreads();

  // ---- per-block colsum (deterministic)
  {
    int k = t & 63, q = t >> 6;
    float ps = 0.f;
#pragma unroll
    for (int rr = 0; rr < RPB / 4; ++rr) ps += z_s[q * (RPB / 4) + rr][k];
    cpart[q][k] = ps;
  }
  __syncthreads();
  if (t < K_) cp[(size_t)blockIdx.x * (B_ * K_) + b * K_ + t] =
      cpart[0][t] + cpart[1][t] + cpart[2][t] + cpart[3][t];

  // ---- mu-update partials: thread = (c_lo = t&127, khd = t>>7); 2 c's per thread
  if (DO_MU) {
    int cl = t & 127, khd = t >> 7;
    float acc2[2][32];
#pragma unroll
    for (int q = 0; q < 2; ++q)
#pragma unroll
      for (int i = 0; i < 32; ++i) acc2[q][i] = 0.f;
    const float* xb = x + ((size_t)b * L_ + l0) * C_ + cl;
    for (int rr = 0; rr < RPB; ++rr) {
      float4 zv[8];
#pragma unroll
      for (int q = 0; q < 8; ++q) zv[q] = *(const float4*)(&z_s[rr][khd * 32 + q * 4]);
      float xv0 = xb[(size_t)rr * C_];
      float xv1 = xb[(size_t)rr * C_ + 128];
#pragma unroll
      for (int q = 0; q < 8; ++q) {
        acc2[0][q*4+0] = fmaf(zv[q].x, xv0, acc2[0][q*4+0]);
        acc2[0][q*4+1] = fmaf(zv[q].y, xv0, acc2[0][q*4+1]);
        acc2[0][q*4+2] = fmaf(zv[q].z, xv0, acc2[0][q*4+2]);
        acc2[0][q*4+3] = fmaf(zv[q].w, xv0, acc2[0][q*4+3]);
        acc2[1][q*4+0] = fmaf(zv[q].x, xv1, acc2[1][q*4+0]);
        acc2[1][q*4+1] = fmaf(zv[q].y, xv1, acc2[1][q*4+1]);
        acc2[1][q*4+2] = fmaf(zv[q].z, xv1, acc2[1][q*4+2]);
        acc2[1][q*4+3] = fmaf(zv[q].w, xv1, acc2[1][q*4+3]);
      }
    }
    float* pp = part + (((size_t)blockIdx.x * B_ + b) * K_ + khd * 32) * C_ + cl;
#pragma unroll
    for (int kk = 0; kk < 32; ++kk) {
      pp[(size_t)kk * C_] = acc2[0][kk];
      pp[(size_t)kk * C_ + 128] = acc2[1][kk];
    }
  }
}

// ---------------------------------------------------------------- k_mufin
template<bool WRITE_OUT>
__global__ __launch_bounds__(64) void k_mufin(
    const float* __restrict__ part, const float* __restrict__ cp,
    float* __restrict__ mu, float* __restrict__ zsA, float* __restrict__ outmu)
{
  int bk = blockIdx.x;     // b*64+k
  int t = threadIdx.x;     // 64
  float4 s = make_float4(0.f, 0.f, 0.f, 0.f);
#pragma unroll
  for (int ch = 0; ch < NCH; ++ch) {
    const float4* p = (const float4*)(part + ((size_t)ch * (B_ * K_) + bk) * C_);
    float4 v = p[t];
    s.x += v.x; s.y += v.y; s.z += v.z; s.w += v.w;
  }
  float zs = 0.f;
#pragma unroll
  for (int ch = 0; ch < NCH; ++ch) zs += cp[(size_t)ch * (B_ * K_) + bk];
  float sc = 1.f / (EPSF + zs);
  s.x *= sc; s.y *= sc; s.z *= sc; s.w *= sc;
  float ssq = s.x * s.x + s.y * s.y + s.z * s.z + s.w * s.w;
#pragma unroll
  for (int off = 32; off >= 1; off >>= 1) ssq += __shfl_xor(ssq, off, 64);
  float inv = 1.f / (EPSF + sqrtf(ssq));
  s.x *= inv; s.y *= inv; s.z *= inv; s.w *= inv;
  ((float4*)(mu + (size_t)bk * C_))[t] = s;
  if (WRITE_OUT) ((float4*)(outmu + (size_t)bk * C_))[t] = s;
  if (t == 0) zsA[bk] = zs;
}

// ---------------------------------------------------------------- k_attn
__global__ __launch_bounds__(256) void k_attn(
    const float* __restrict__ zB, const float* __restrict__ cpB, float* __restrict__ attn)
{
  __shared__ float zt[64][68];
  __shared__ float inv_s[K_];
  int b = blockIdx.y, l0 = blockIdx.x * 64;
  int t = threadIdx.x;
  if (t < K_) {
    float zs = 0.f;
#pragma unroll
    for (int ch = 0; ch < NCH; ++ch) zs += cpB[(size_t)ch * (B_ * K_) + b * K_ + t];
    inv_s[t] = 1.f / (EPSF + zs);
  }
  for (int p = 0; p < 16; ++p) {
    int e = t + p * 256; int lo = e >> 6, k = e & 63;
    zt[lo][k] = zB[((size_t)b * L_ + l0 + lo) * K_ + k];
  }
  __syncthreads();
  int lo = t & 63, kb = t >> 6;
  for (int p = 0; p < 16; ++p) {
    int k = kb * 16 + p;
    attn[((size_t)b * K_ + k) * L_ + l0 + lo] = zt[lo][k] * inv_s[k];
  }
}

// ---------------------------------------------------------------- k_recon
__global__ __launch_bounds__(256) void k_recon(
    const float* __restrict__ zA, const float* __restrict__ zsA,
    const float* __restrict__ mu, unsigned short* __restrict__ reconbf)
{
  __shared__ float mu_s[K_ * C_];   // 64KB
  __shared__ float zn[16][68];
  __shared__ float zinv[K_];
  int b = blockIdx.y, l0 = blockIdx.x * 128;
  int t = threadIdx.x;
  {
    const float4* msrc = (const float4*)(mu + (size_t)b * K_ * C_);
    for (int e = t; e < K_ * C_ / 4; e += 256) ((float4*)mu_s)[e] = msrc[e];
  }
  if (t < K_) zinv[t] = 1.f / (EPSF + zsA[b * K_ + t]);
  __syncthreads();
  for (int batch = 0; batch < 8; ++batch) {
    for (int e = t; e < 1024; e += 256) {
      int rr = e >> 6, k = e & 63;
      zn[rr][k] = zA[((size_t)b * L_ + l0 + batch * 16 + rr) * K_ + k] * zinv[k];
    }
    __syncthreads();
    for (int rr = 0; rr < 16; ++rr) {
      float a = 0.f;
#pragma unroll
      for (int k4 = 0; k4 < 16; ++k4) {
        float4 z4 = *(const float4*)(&zn[rr][k4 * 4]);
        a = fmaf(z4.x, mu_s[(k4 * 4 + 0) * C_ + t], a);
        a = fmaf(z4.y, mu_s[(k4 * 4 + 1) * C_ + t], a);
        a = fmaf(z4.z, mu_s[(k4 * 4 + 2) * C_ + t], a);
        a = fmaf(z4.w, mu_s[(k4 * 4 + 3) * C_ + t], a);
      }
      reconbf[((size_t)b * L_ + l0 + batch * 16 + rr) * C_ + t] = f2bf(a);
    }
    __syncthreads();
  }
}

// ---------------------------------------------------------------- k_mlp
// fused: out = relu(bn(recon @ w1^T)) @ w2^T + b2, bf16 MFMA 16x16x32
// ICH=32; staging via global_load_lds (pre-swizzled global src, linear LDS dst)
__global__ __launch_bounds__(256, 2) void k_mlp(
    const unsigned short* __restrict__ reconbf,  // [BL][256]
    const unsigned short* __restrict__ w1bf,     // [4096][256]
    const unsigned short* __restrict__ w2bf,     // [256][4096]
    const float* __restrict__ bnsc, const float* __restrict__ bnsh,
    const float* __restrict__ b2, float* __restrict__ outr)  // [BL][256]
{
  __shared__ unsigned short w1s[ICH * 256];   // 16KB [i][c], slot16: c8 ^= (i&7)
  __shared__ unsigned short w2s[256 * ICH];   // 16KB [o][i], slot16: i8 ^= (o&3)
  __shared__ unsigned short hs[64 * 48];      // 6KB  [tok][i], padded 32->48

  int t = threadIdx.x;
  int w = t >> 6, lane = t & 63;
  int l15 = lane & 15, l4 = lane >> 4;
  int rb = blockIdx.x * 64;
  int wm = w & 1, wi = w >> 1;               // GEMM1: wm = 32-tok half, wi = 16-i half

  // persistent A1 fragments (recon rows, full C=256)
  bf16x8 a1[2][8];
#pragma unroll
  for (int mt = 0; mt < 2; ++mt)
#pragma unroll
    for (int ck = 0; ck < 8; ++ck)
      a1[mt][ck] = *(const bf16x8*)(reconbf +
          ((size_t)(rb + wm * 32 + mt * 16 + l15)) * C_ + ck * 32 + l4 * 8);

  f32x4 zero4 = {0.f, 0.f, 0.f, 0.f};
  f32x4 acc2[4][4];
#pragma unroll
  for (int mt = 0; mt < 4; ++mt)
#pragma unroll
    for (int nt = 0; nt < 4; ++nt) acc2[mt][nt] = zero4;

  for (int ic = 0; ic < INNER_ / ICH; ++ic) {
    __syncthreads();   // prior reads of w1s/w2s/hs done
    // ---- async stage: w1 chunk [32 i][256 c], 1024 x 16B slots
#pragma unroll
    for (int q = 0; q < 4; ++q) {
      int s = q * 256 + t;
      int i = s >> 5, c8s = s & 31;
      const unsigned short* src =
          w1bf + ((size_t)(ic * ICH + i)) * C_ + (c8s ^ (i & 7)) * 8;
      __builtin_amdgcn_global_load_lds(
          (const __attribute__((address_space(1))) unsigned*)src,
          (__attribute__((address_space(3))) unsigned*)(w1s + (size_t)s * 8), 16, 0, 0);
    }
    // ---- async stage: w2 chunk [256 o][32 i], 1024 x 16B slots
#pragma unroll
    for (int q = 0; q < 4; ++q) {
      int s = q * 256 + t;
      int o = s >> 2, i8s = s & 3;
      const unsigned short* src =
          w2bf + (size_t)o * INNER_ + ic * ICH + (i8s ^ (o & 3)) * 8;
      __builtin_amdgcn_global_load_lds(
          (const __attribute__((address_space(1))) unsigned*)src,
          (__attribute__((address_space(3))) unsigned*)(w2s + (size_t)s * 8), 16, 0, 0);
    }
    __syncthreads();   // staging complete (vmcnt drained at barrier)

    // ---- GEMM1: h-chunk [64 tok][32 i]; wave quadrant (wm: tok, wi: i)
    f32x4 acc1[2];
#pragma unroll
    for (int mt = 0; mt < 2; ++mt) acc1[mt] = zero4;
    int iloc = wi * 16 + l15;
#pragma unroll
    for (int ck = 0; ck < 8; ++ck) {
      bf16x8 bfr = *(const bf16x8*)(w1s + iloc * 256 + ((ck * 4 + l4) ^ (iloc & 7)) * 8);
#pragma unroll
      for (int mt = 0; mt < 2; ++mt)
        acc1[mt] = __builtin_amdgcn_mfma_f32_16x16x32_bf16(
            a1[mt][ck], bfr, acc1[mt], 0, 0, 0);
    }

    // ---- BN + ReLU + bf16 -> hs [tok][i] (padded 48)
    {
      int ig = ic * ICH + iloc;
      float sc = bnsc[ig], sh = bnsh[ig];
#pragma unroll
      for (int mt = 0; mt < 2; ++mt) {
#pragma unroll
        for (int j = 0; j < 4; ++j) {
          int tok = wm * 32 + mt * 16 + l4 * 4 + j;
          float v = fmaxf(fmaf(acc1[mt][j], sc, sh), 0.f);
          hs[tok * 48 + iloc] = f2bf(v);
        }
      }
    }
    __syncthreads();   // hs visible to all waves

    // ---- GEMM2: acc2 += h @ w2^T (k = 32 = one MFMA)
    bf16x8 a2[4];
#pragma unroll
    for (int mt = 0; mt < 4; ++mt) {
      int tok = mt * 16 + l15;
      a2[mt] = *(const bf16x8*)(hs + tok * 48 + l4 * 8);
    }
#pragma unroll
    for (int nt = 0; nt < 4; ++nt) {
      int o = w * 64 + nt * 16 + l15;
      bf16x8 b2f = *(const bf16x8*)(w2s + o * ICH + (l4 ^ (o & 3)) * 8);
#pragma unroll
      for (int mt = 0; mt < 4; ++mt)
        acc2[mt][nt] = __builtin_amdgcn_mfma_f32_16x16x32_bf16(
            a2[mt], b2f, acc2[mt][nt], 0, 0, 0);
    }
  }

  // epilogue: + b2, store f32
#pragma unroll
  for (int nt = 0; nt < 4; ++nt) {
    int o = w * 64 + nt * 16 + l15;
    float bias = b2[o];
#pragma unroll
    for (int mt = 0; mt < 4; ++mt) {
#pragma unroll
      for (int j = 0; j < 4; ++j) {
        int row = rb + mt * 16 + l4 * 4 + j;
        outr[(size_t)row * C_ + o] = acc2[mt][nt][j] + bias;
      }
    }
  }
}

// ---------------------------------------------------------------- launch
extern "C" void kernel_launch(void* const* d_in, const int* in_sizes, int n_in,
                              void* d_out, int out_size, void* d_ws, size_t ws_size,
                              hipStream_t stream)
{
  const float* x     = (const float*)d_in[0];
  const float* mu0   = (const float*)d_in[2];
  const float* w1    = (const float*)d_in[3];
  const float* b1    = (const float*)d_in[4];
  const float* gamma = (const float*)d_in[5];
  const float* beta  = (const float*)d_in[6];
  const float* bmean = (const float*)d_in[7];
  const float* bvar  = (const float*)d_in[8];
  const float* w2    = (const float*)d_in[9];
  const float* b2    = (const float*)d_in[10];
  float* out = (float*)d_out;

  float* ws = (float*)d_ws;
  float* muB  = ws + 0;         // 262144
  float* zA   = ws + 262144;    // 2097152
  float* zB   = ws + 2359296;   // 2097152
  float* zsA  = ws + 4456448;   // 1024
  float* cpA  = ws + 4457472;   // 16384
  float* cpB  = ws + 4473856;   // 16384
  float* bnsc = ws + 4490240;   // 4096
  float* bnsh = ws + 4494336;   // 4096
  float* part = ws + 4498432;   // 4194304
  float* xT   = ws + 8692736;   // 8388608
  unsigned short* reconbf = (unsigned short*)(ws + 17081344);  // 4194304 bf16
  unsigned short* w1bf    = (unsigned short*)(ws + 19178496);  // 1048576 bf16
  unsigned short* w2bf    = (unsigned short*)(ws + 19702784);  // 1048576 bf16
  // total: 20227072 floats = 80.9 MB

  k_pre<<<4096, 256, 0, stream>>>(w1, w2, gamma, beta, bmean, bvar, b1, mu0,
                                  w1bf, w2bf, bnsc, bnsh, muB);
  k_xT<<<dim3(32, 4, 16), 256, 0, stream>>>(x, xT);

  for (int s = 0; s < 10; ++s) {
    k_em<true><<<dim3(NCH, B_), 256, 0, stream>>>(xT, x, muB, zA, cpA, part);
    if (s == 9) k_mufin<true ><<<1024, 64, 0, stream>>>(part, cpA, muB, zsA, out);
    else        k_mufin<false><<<1024, 64, 0, stream>>>(part, cpA, muB, zsA, out);
  }
  // new_z with final mu
  k_em<false><<<dim3(NCH, B_), 256, 0, stream>>>(xT, x, muB, zB, cpB, part);
  k_attn<<<dim3(32, B_), 256, 0, stream>>>(zB, cpB, out + 262144);
  k_recon<<<dim3(16, B_), 256, 0, stream>>>(zA, zsA, muB, reconbf);
  k_mlp<<<512, 256, 0, stream>>>(reconbf, w1bf, w2bf, bnsc, bnsh, b2, out + 2359296);
}

// Round 3
// 541.139 us; speedup vs baseline: 4.1211x; 4.1211x over previous
//
#include <hip/hip_runtime.h>

constexpr int B_ = 16, L_ = 2048, C_ = 256, K_ = 64, INNER_ = 4096;
constexpr int NCH = 16;          // L-chunks
constexpr int RPB = 128;         // rows per k_em block
#define EPSF 1e-6f

typedef __attribute__((ext_vector_type(8)))  short bf16x8;
typedef __attribute__((ext_vector_type(4)))  float f32x4;
typedef __attribute__((ext_vector_type(16))) float f32x16;
typedef _Float16 f16;
typedef __attribute__((ext_vector_type(8))) _Float16 f16x8;
typedef __attribute__((ext_vector_type(4))) _Float16 f16x4;

__device__ __forceinline__ unsigned short f2bf(float f) {
  union { float f; unsigned u; } v; v.f = f;
  unsigned r = v.u + 0x7fffu + ((v.u >> 16) & 1u);   // RNE
  return (unsigned short)(r >> 16);
}

__device__ __forceinline__ void gload16(const void* src, void* lds) {
  __builtin_amdgcn_global_load_lds(
      (const __attribute__((address_space(1))) unsigned*)src,
      (__attribute__((address_space(3))) unsigned*)lds, 16, 0, 0);
}

// ---------------------------------------------------------------- k_pre
// w1bf = bf16(w1 * bn_scale_row) (BN scale folded into w1); w2bf; bnsh; muF init
__global__ __launch_bounds__(256) void k_pre(
    const float* __restrict__ w1, const float* __restrict__ w2,
    const float* __restrict__ gamma, const float* __restrict__ beta,
    const float* __restrict__ bmean, const float* __restrict__ bvar,
    const float* __restrict__ b1, const float* __restrict__ mu0,
    unsigned short* __restrict__ w1bf, unsigned short* __restrict__ w2bf,
    float* __restrict__ bnsh, f16* __restrict__ muF)
{
  int i = blockIdx.x * 256 + threadIdx.x;     // covers 1048576
  if (i < INNER_ * C_) {
    int r = i >> 8;
    float sc = gamma[r] * rsqrtf(bvar[r] + 1e-5f);
    w1bf[i] = f2bf(w1[i] * sc);
    w2bf[i] = f2bf(w2[i]);
  }
  if (i < B_ * K_ * C_) muF[i] = (f16)mu0[i & (K_ * C_ - 1)];
  if (i < INNER_) {
    float sc = gamma[i] * rsqrtf(bvar[i] + 1e-5f);
    bnsh[i] = fmaf(b1[i] - bmean[i], sc, beta[i]);
  }
}

// ---------------------------------------------------------------- k_split
// x fp32 -> xf fp16 [B][L][C]
__global__ __launch_bounds__(256) void k_split(const float* __restrict__ x, f16* __restrict__ xf)
{
  size_t i = (size_t)blockIdx.x * 256 + threadIdx.x;   // 2,097,152 float4s
  float4 v = ((const float4*)x)[i];
  f16x4 o; o[0] = (f16)v.x; o[1] = (f16)v.y; o[2] = (f16)v.z; o[3] = (f16)v.w;
  ((f16x4*)xf)[i] = o;
}

// ---------------------------------------------------------------- k_xT
// x [B][L][C] -> xTf fp16 [B][C][L]
__global__ __launch_bounds__(256) void k_xT(const float* __restrict__ x, f16* __restrict__ xTf)
{
  __shared__ float ts[64][65];
  int l0 = blockIdx.x * 64, c0 = blockIdx.y * 64, b = blockIdx.z;
  int t = threadIdx.x;
  for (int p = 0; p < 16; ++p) {
    int e = t + p * 256, i = e >> 6, j = e & 63;
    ts[i][j] = x[((size_t)b * L_ + l0 + i) * C_ + c0 + j];
  }
  __syncthreads();
  for (int p = 0; p < 16; ++p) {
    int e = t + p * 256, i = e >> 6, j = e & 63;
    xTf[((size_t)b * C_ + c0 + i) * L_ + l0 + j] = (f16)ts[j][i];
  }
}

// ---------------------------------------------------------------- k_em
// per (b, 128-row chunk): S^T = mu.x^T (MFMA) -> softmax (in-reg) -> z
// -> colsum partial -> part[k][c] += z^T.x (MFMA).  All fp16 inputs, fp32 math.
template<bool DO_MU, bool WRITE_Z>
__global__ __launch_bounds__(256) void k_em(
    const f16* __restrict__ xf,    // [B][L][C]
    const f16* __restrict__ xTf,   // [B][C][L]
    const f16* __restrict__ muF,   // [B][K][C]
    f16* __restrict__ zout,        // [B][L][K]
    float* __restrict__ cp,        // [NCH][B*K]
    f16* __restrict__ part)        // [NCH][B][K][C]
{
  __shared__ f16 mu_s[K_ * C_];    // 32KB, slot-swizzled ^(k&15)
  __shared__ f16 zT_s[K_ * RPB];   // 16KB, slot-swizzled ^(k&15)
  __shared__ float cpart[4][K_];

  int t = threadIdx.x, b = blockIdx.y, chn = blockIdx.x, l0 = chn * RPB;
  int w = t >> 6, lane = t & 63, l15 = lane & 15, g = lane >> 4;

  // stage mu (32KB): linear LDS dest, pre-swizzled global source (slot ^ (k&15))
#pragma unroll
  for (int q = 0; q < 8; ++q) {
    int s = q * 256 + t, k = s >> 5, sl = s & 31;
    gload16(muF + (size_t)b * (K_ * C_) + k * C_ + ((sl ^ (k & 15)) << 3), mu_s + s * 8);
  }
  __syncthreads();

  // ---- phase1: S^T[k][tok]  (wave w owns tok tiles 2w, 2w+1)
  f32x4 acc[4][2];
#pragma unroll
  for (int mt = 0; mt < 4; ++mt)
#pragma unroll
    for (int n = 0; n < 2; ++n)
#pragma unroll
      for (int j = 0; j < 4; ++j) acc[mt][n][j] = 0.f;

  const f16* xr0 = xf + ((size_t)b * L_ + l0 + (w * 2 + 0) * 16 + l15) * C_ + g * 8;
  const f16* xr1 = xf + ((size_t)b * L_ + l0 + (w * 2 + 1) * 16 + l15) * C_ + g * 8;
#pragma unroll
  for (int ck = 0; ck < 8; ++ck) {
    f16x8 xb0 = *(const f16x8*)(xr0 + ck * 32);
    f16x8 xb1 = *(const f16x8*)(xr1 + ck * 32);
#pragma unroll
    for (int mt = 0; mt < 4; ++mt) {
      f16x8 a = *(const f16x8*)(mu_s + (mt * 16 + l15) * C_ + (((ck * 4 + g) ^ l15) << 3));
      acc[mt][0] = __builtin_amdgcn_mfma_f32_16x16x32_f16(a, xb0, acc[mt][0], 0, 0, 0);
      acc[mt][1] = __builtin_amdgcn_mfma_f32_16x16x32_f16(a, xb1, acc[mt][1], 0, 0, 0);
    }
  }

  // ---- phase2: softmax over k (rows); lane holds [k = mt*16+g*4+jj][tok]
  float z[4][4][2];
#pragma unroll
  for (int n = 0; n < 2; ++n) {
    float mx = acc[0][n][0];
#pragma unroll
    for (int mt = 0; mt < 4; ++mt)
#pragma unroll
      for (int jj = 0; jj < 4; ++jj) mx = fmaxf(mx, acc[mt][n][jj]);
    mx = fmaxf(mx, __shfl_xor(mx, 16, 64));
    mx = fmaxf(mx, __shfl_xor(mx, 32, 64));
    float sm = 0.f;
#pragma unroll
    for (int mt = 0; mt < 4; ++mt)
#pragma unroll
      for (int jj = 0; jj < 4; ++jj) {
        float e = __expf(acc[mt][n][jj] - mx);
        z[mt][jj][n] = e; sm += e;
      }
    sm += __shfl_xor(sm, 16, 64);
    sm += __shfl_xor(sm, 32, 64);
    float inv = 1.f / sm;
#pragma unroll
    for (int mt = 0; mt < 4; ++mt)
#pragma unroll
      for (int jj = 0; jj < 4; ++jj) z[mt][jj][n] *= inv;
  }

  // colsum over this chunk's 128 rows (butterfly over l15 then cross-wave LDS)
#pragma unroll
  for (int mt = 0; mt < 4; ++mt)
#pragma unroll
    for (int jj = 0; jj < 4; ++jj) {
      float v = z[mt][jj][0] + z[mt][jj][1];
      v += __shfl_xor(v, 1, 64); v += __shfl_xor(v, 2, 64);
      v += __shfl_xor(v, 4, 64); v += __shfl_xor(v, 8, 64);
      if (l15 == 0) cpart[w][mt * 16 + g * 4 + jj] = v;
    }
  __syncthreads();
  if (t < K_) cp[(size_t)chn * (B_ * K_) + b * K_ + t] =
      cpart[0][t] + cpart[1][t] + cpart[2][t] + cpart[3][t];

  // write z^T to LDS (swizzled) and z to global
#pragma unroll
  for (int mt = 0; mt < 4; ++mt)
#pragma unroll
    for (int jj = 0; jj < 4; ++jj)
#pragma unroll
      for (int n = 0; n < 2; ++n) {
        int k = mt * 16 + g * 4 + jj;
        int tl = (w * 2 + n) * 16 + l15;
        f16 h = (f16)z[mt][jj][n];
        if (DO_MU)   zT_s[k * RPB + (((tl >> 3) ^ (k & 15)) << 3) + (tl & 7)] = h;
        if (WRITE_Z) zout[((size_t)b * L_ + l0 + tl) * K_ + k] = h;
      }

  // ---- phase3: part[k][c] = z^T . xT  (wave w owns c-quarter w*64)
  if (DO_MU) {
    __syncthreads();
    f32x4 a3[4][4];
#pragma unroll
    for (int mt = 0; mt < 4; ++mt)
#pragma unroll
      for (int nt = 0; nt < 4; ++nt)
#pragma unroll
        for (int j = 0; j < 4; ++j) a3[mt][nt][j] = 0.f;
    int cb = w * 64;
#pragma unroll
    for (int ks = 0; ks < 4; ++ks) {
      f16x8 az[4], bx[4];
#pragma unroll
      for (int mt = 0; mt < 4; ++mt)
        az[mt] = *(const f16x8*)(zT_s + (mt * 16 + l15) * RPB + (((ks * 4 + g) ^ l15) << 3));
#pragma unroll
      for (int nt = 0; nt < 4; ++nt)
        bx[nt] = *(const f16x8*)(xTf + ((size_t)b * C_ + cb + nt * 16 + l15) * L_ + l0 + ks * 32 + g * 8);
#pragma unroll
      for (int mt = 0; mt < 4; ++mt)
#pragma unroll
        for (int nt = 0; nt < 4; ++nt)
          a3[mt][nt] = __builtin_amdgcn_mfma_f32_16x16x32_f16(az[mt], bx[nt], a3[mt][nt], 0, 0, 0);
    }
    f16* pp = part + (((size_t)chn * B_ + b) * K_) * C_;
#pragma unroll
    for (int mt = 0; mt < 4; ++mt)
#pragma unroll
      for (int nt = 0; nt < 4; ++nt)
#pragma unroll
        for (int jj = 0; jj < 4; ++jj)
          pp[(size_t)(mt * 16 + g * 4 + jj) * C_ + cb + nt * 16 + l15] = (f16)a3[mt][nt][jj];
  }
}

// ---------------------------------------------------------------- k_mufin
// block = (b, k-group-of-4): reduce 16 chunk-partials, colsum-scale, L2-normalize
template<bool LAST>
__global__ __launch_bounds__(256) void k_mufin(
    const f16* __restrict__ part, const float* __restrict__ cp,
    float* __restrict__ muB, f16* __restrict__ muF,
    float* __restrict__ zsA, float* __restrict__ outmu)
{
  int b = blockIdx.x >> 4, kg = blockIdx.x & 15, t = threadIdx.x;
  int kr = t >> 6, c4 = t & 63, k = kg * 4 + kr;
  float a0 = 0.f, a1 = 0.f, a2 = 0.f, a3 = 0.f;
#pragma unroll
  for (int chn = 0; chn < NCH; ++chn) {
    f16x4 p = *(const f16x4*)(part + (((size_t)chn * B_ + b) * K_ + k) * C_ + c4 * 4);
    a0 += (float)p[0]; a1 += (float)p[1]; a2 += (float)p[2]; a3 += (float)p[3];
  }
  float zs = 0.f;
#pragma unroll
  for (int chn = 0; chn < NCH; ++chn) zs += cp[(size_t)chn * (B_ * K_) + b * K_ + k];
  float sc = 1.f / (EPSF + zs);
  a0 *= sc; a1 *= sc; a2 *= sc; a3 *= sc;
  float ssq = a0 * a0 + a1 * a1 + a2 * a2 + a3 * a3;
#pragma unroll
  for (int off = 32; off >= 1; off >>= 1) ssq += __shfl_xor(ssq, off, 64);
  float inv = 1.f / (EPSF + sqrtf(ssq));
  a0 *= inv; a1 *= inv; a2 *= inv; a3 *= inv;
  size_t base = (size_t)(b * K_ + k) * C_ + c4 * 4;
  float4 o = make_float4(a0, a1, a2, a3);
  *(float4*)(muB + base) = o;
  f16x4 hm; hm[0] = (f16)a0; hm[1] = (f16)a1; hm[2] = (f16)a2; hm[3] = (f16)a3;
  *(f16x4*)(muF + base) = hm;
  if (c4 == 0) zsA[b * K_ + k] = zs;
  if (LAST) *(float4*)(outmu + base) = o;
}

// ---------------------------------------------------------------- k_attn
__global__ __launch_bounds__(256) void k_attn(
    const f16* __restrict__ zB, const float* __restrict__ cpB, float* __restrict__ attn)
{
  __shared__ float zt[64][68];
  __shared__ float inv_s[K_];
  int b = blockIdx.y, l0 = blockIdx.x * 64, t = threadIdx.x;
  if (t < K_) {
    float zs = 0.f;
#pragma unroll
    for (int chn = 0; chn < NCH; ++chn) zs += cpB[(size_t)chn * (B_ * K_) + b * K_ + t];
    inv_s[t] = 1.f / (EPSF + zs);
  }
  for (int p = 0; p < 16; ++p) {
    int e = t + p * 256, lo = e >> 6, k = e & 63;
    zt[lo][k] = (float)zB[((size_t)b * L_ + l0 + lo) * K_ + k];
  }
  __syncthreads();
  int lo = t & 63, kb = t >> 6;
  for (int p = 0; p < 16; ++p) {
    int k = kb * 16 + p;
    attn[((size_t)b * K_ + k) * L_ + l0 + lo] = zt[lo][k] * inv_s[k];
  }
}

// ---------------------------------------------------------------- k_recon
__global__ __launch_bounds__(256) void k_recon(
    const f16* __restrict__ zA, const float* __restrict__ zsA,
    const float* __restrict__ muB, unsigned short* __restrict__ reconbf)
{
  __shared__ float mu_s[K_ * C_];   // 64KB
  __shared__ float zn[16][68];
  __shared__ float zinv[K_];
  int b = blockIdx.y, l0 = blockIdx.x * 128, t = threadIdx.x;
  {
    const float4* msrc = (const float4*)(muB + (size_t)b * K_ * C_);
    for (int e = t; e < K_ * C_ / 4; e += 256) ((float4*)mu_s)[e] = msrc[e];
  }
  if (t < K_) zinv[t] = 1.f / (EPSF + zsA[b * K_ + t]);
  __syncthreads();
  for (int batch = 0; batch < 8; ++batch) {
    for (int e = t; e < 1024; e += 256) {
      int rr = e >> 6, k = e & 63;
      zn[rr][k] = (float)zA[((size_t)b * L_ + l0 + batch * 16 + rr) * K_ + k] * zinv[k];
    }
    __syncthreads();
    for (int rr = 0; rr < 16; ++rr) {
      float a = 0.f;
#pragma unroll
      for (int k4 = 0; k4 < 16; ++k4) {
        float4 z4 = *(const float4*)(&zn[rr][k4 * 4]);
        a = fmaf(z4.x, mu_s[(k4 * 4 + 0) * C_ + t], a);
        a = fmaf(z4.y, mu_s[(k4 * 4 + 1) * C_ + t], a);
        a = fmaf(z4.z, mu_s[(k4 * 4 + 2) * C_ + t], a);
        a = fmaf(z4.w, mu_s[(k4 * 4 + 3) * C_ + t], a);
      }
      reconbf[((size_t)b * L_ + l0 + batch * 16 + rr) * C_ + t] = f2bf(a);
    }
    __syncthreads();
  }
}

// ---------------------------------------------------------------- k_mlp
// out = relu(recon @ w1s^T + bnsh) @ w2^T + b2 ; 32x32x16 MFMA, 128 tok/block,
// recon frags persistent in regs, dbuf weight staging, lgkm-only mid barrier.
__global__ __launch_bounds__(256, 1) void k_mlp(
    const unsigned short* __restrict__ reconbf,  // [BL][256] bf16
    const unsigned short* __restrict__ w1bf,     // [4096][256] bf16 (bn-scaled)
    const unsigned short* __restrict__ w2bf,     // [256][4096] bf16
    const float* __restrict__ bnsh, const float* __restrict__ b2,
    float* __restrict__ outr)                    // [BL][256] f32
{
  __shared__ unsigned short w1s[2][32 * 256];  // 2x16KB, slot ^ (i&15)
  __shared__ unsigned short w2s[2][256 * 32];  // 2x16KB, slot ^ (o&3)
  __shared__ unsigned short hs[128 * 40];      // 10KB  [tok][i], stride 40

  int t = threadIdx.x, w = t >> 6, lane = t & 63, l31 = lane & 31, l5 = lane >> 5;
  int rb = blockIdx.x * 128;

  // persistent recon B-frags (tok = rb + w*32 + l31, full C)
  bf16x8 rc[16];
  const unsigned short* rrow = reconbf + (size_t)(rb + w * 32 + l31) * C_ + l5 * 8;
#pragma unroll
  for (int ks = 0; ks < 16; ++ks) rc[ks] = *(const bf16x8*)(rrow + ks * 16);

  f32x16 acc2[2][4];
#pragma unroll
  for (int oi = 0; oi < 2; ++oi)
#pragma unroll
    for (int ti = 0; ti < 4; ++ti)
#pragma unroll
      for (int r = 0; r < 16; ++r) acc2[oi][ti][r] = 0.f;

#define STAGE(ic, buf)                                                          \
  {                                                                             \
    _Pragma("unroll")                                                           \
    for (int q = 0; q < 4; ++q) {                                               \
      int s = q * 256 + t, i = s >> 5, sl = s & 31;                             \
      gload16(w1bf + (size_t)((ic) * 32 + i) * C_ + ((sl ^ (i & 15)) << 3),     \
              w1s[buf] + s * 8);                                                \
    }                                                                           \
    _Pragma("unroll")                                                           \
    for (int q = 0; q < 4; ++q) {                                               \
      int s = q * 256 + t, o = s >> 2, sl = s & 3;                              \
      gload16(w2bf + (size_t)o * INNER_ + (ic) * 32 + ((sl ^ (o & 3)) << 3),    \
              w2s[buf] + s * 8);                                                \
    }                                                                           \
  }

  STAGE(0, 0);
  __syncthreads();

  for (int ic = 0; ic < 128; ++ic) {
    int cur = ic & 1;
    if (ic < 127) STAGE(ic + 1, cur ^ 1);

    // GEMM1: h^[i][tok] for this wave's 32 toks; two interleaved acc chains
    f32x16 h0, h1;
#pragma unroll
    for (int r = 0; r < 16; ++r) { h0[r] = 0.f; h1[r] = 0.f; }
#pragma unroll
    for (int ks = 0; ks < 16; ++ks) {
      bf16x8 a1 = *(const bf16x8*)(w1s[cur] + l31 * 256 + (((ks * 2 + l5) ^ (l31 & 15)) << 3));
      if (ks & 1) h1 = __builtin_amdgcn_mfma_f32_32x32x16_bf16(a1, rc[ks], h1, 0, 0, 0);
      else        h0 = __builtin_amdgcn_mfma_f32_32x32x16_bf16(a1, rc[ks], h0, 0, 0, 0);
    }
#pragma unroll
    for (int r = 0; r < 16; ++r) h0[r] += h1[r];

    // BN shift + ReLU -> hs[tok][i]
#pragma unroll
    for (int r = 0; r < 16; ++r) {
      int il = (r & 3) + 8 * (r >> 2) + 4 * l5;
      float v = fmaxf(h0[r] + bnsh[ic * 32 + il], 0.f);
      hs[(w * 32 + l31) * 40 + il] = f2bf(v);
    }
    // hs ready: drain LDS only — staged global_load_lds stays in flight
    asm volatile("s_waitcnt lgkmcnt(0)" ::: "memory");
    __builtin_amdgcn_s_barrier();

    // GEMM2: wave owns o in [w*64, w*64+64), all 128 toks, K=32
#pragma unroll
    for (int ks2 = 0; ks2 < 2; ++ks2) {
      bf16x8 a2[2], bh[4];
#pragma unroll
      for (int oi = 0; oi < 2; ++oi) {
        int o = w * 64 + oi * 32 + l31;
        a2[oi] = *(const bf16x8*)(w2s[cur] + o * 32 + (((ks2 * 2 + l5) ^ (o & 3)) << 3));
      }
#pragma unroll
      for (int ti = 0; ti < 4; ++ti)
        bh[ti] = *(const bf16x8*)(hs + (ti * 32 + l31) * 40 + ks2 * 16 + l5 * 8);
#pragma unroll
      for (int oi = 0; oi < 2; ++oi)
#pragma unroll
        for (int ti = 0; ti < 4; ++ti)
          acc2[oi][ti] = __builtin_amdgcn_mfma_f32_32x32x16_bf16(a2[oi], bh[ti], acc2[oi][ti], 0, 0, 0);
    }
    __syncthreads();   // drains vmcnt: next buffers staged; cur fully consumed
  }

  // epilogue: + b2, store
#pragma unroll
  for (int oi = 0; oi < 2; ++oi)
#pragma unroll
    for (int r = 0; r < 16; ++r) {
      int o = w * 64 + oi * 32 + (r & 3) + 8 * (r >> 2) + 4 * l5;
      float bias = b2[o];
#pragma unroll
      for (int ti = 0; ti < 4; ++ti) {
        int tok = rb + ti * 32 + l31;
        outr[(size_t)tok * C_ + o] = acc2[oi][ti][r] + bias;
      }
    }
#undef STAGE
}

// ---------------------------------------------------------------- launch
extern "C" void kernel_launch(void* const* d_in, const int* in_sizes, int n_in,
                              void* d_out, int out_size, void* d_ws, size_t ws_size,
                              hipStream_t stream)
{
  const float* x     = (const float*)d_in[0];
  const float* mu0   = (const float*)d_in[2];
  const float* w1    = (const float*)d_in[3];
  const float* b1    = (const float*)d_in[4];
  const float* gamma = (const float*)d_in[5];
  const float* beta  = (const float*)d_in[6];
  const float* bmean = (const float*)d_in[7];
  const float* bvar  = (const float*)d_in[8];
  const float* w2    = (const float*)d_in[9];
  const float* b2    = (const float*)d_in[10];
  float* out = (float*)d_out;

  char* wsb = (char*)d_ws;
  f16* part = (f16*)(wsb + 0);                                  // 8,388,608 B
  f16* zB   = part;                                             // alias (after last mufin)
  f16* zA   = (f16*)(wsb + 8388608);                            // 4,194,304
  f16* xf   = (f16*)(wsb + 12582912);                           // 16,777,216
  f16* xTf  = (f16*)(wsb + 29360128);                           // 16,777,216
  unsigned short* reconbf = (unsigned short*)(wsb + 46137344);  // 16,777,216
  unsigned short* w1bf    = (unsigned short*)(wsb + 62914560);  // 2,097,152
  unsigned short* w2bf    = (unsigned short*)(wsb + 65011712);  // 2,097,152
  f16*   muF  = (f16*)(wsb + 67108864);                         // 524,288
  float* muB  = (float*)(wsb + 67633152);                       // 1,048,576
  float* bnsh = (float*)(wsb + 68681728);                       // 16,384
  float* cpA  = (float*)(wsb + 68698112);                       // 65,536
  float* cpB  = (float*)(wsb + 68763648);                       // 65,536
  float* zsA  = (float*)(wsb + 68829184);                       // 4,096  (total ~68.8MB)

  k_pre<<<4096, 256, 0, stream>>>(w1, w2, gamma, beta, bmean, bvar, b1, mu0,
                                  w1bf, w2bf, bnsh, muF);
  k_split<<<8192, 256, 0, stream>>>(x, xf);
  k_xT<<<dim3(32, 4, 16), 256, 0, stream>>>(x, xTf);

  for (int s = 0; s < 10; ++s) {
    if (s == 9) k_em<true, true ><<<dim3(16, 16), 256, 0, stream>>>(xf, xTf, muF, zA, cpA, part);
    else        k_em<true, false><<<dim3(16, 16), 256, 0, stream>>>(xf, xTf, muF, zA, cpA, part);
    if (s == 9) k_mufin<true ><<<256, 256, 0, stream>>>(part, cpA, muB, muF, zsA, out);
    else        k_mufin<false><<<256, 256, 0, stream>>>(part, cpA, muB, muF, zsA, out);
  }
  // new_z with final mu (no mu-update; zB overlays dead part buffer)
  k_em<false, true><<<dim3(16, 16), 256, 0, stream>>>(xf, xTf, muF, zB, cpB, part);
  k_attn<<<dim3(32, 16), 256, 0, stream>>>(zB, cpB, out + 262144);
  k_recon<<<dim3(16, 16), 256, 0, stream>>>(zA, zsA, muB, reconbf);
  k_mlp<<<256, 256, 0, stream>>>(reconbf, w1bf, w2bf, bnsh, b2, out + 2359296);
}

// Round 4
// 448.898 us; speedup vs baseline: 4.9679x; 1.2055x over previous
//
#include <hip/hip_runtime.h>

constexpr int B_ = 16, L_ = 2048, C_ = 256, K_ = 64, INNER_ = 4096;
constexpr int NCH = 16;          // L-chunks
constexpr int RPB = 128;         // rows per k_em block
#define EPSF 1e-6f

typedef __attribute__((ext_vector_type(8)))  short bf16x8;
typedef __attribute__((ext_vector_type(4)))  float f32x4;
typedef __attribute__((ext_vector_type(16))) float f32x16;
typedef _Float16 f16;
typedef __attribute__((ext_vector_type(8))) _Float16 f16x8;
typedef __attribute__((ext_vector_type(4))) _Float16 f16x4;

__device__ __forceinline__ unsigned short f2bf(float f) {
  union { float f; unsigned u; } v; v.f = f;
  unsigned r = v.u + 0x7fffu + ((v.u >> 16) & 1u);   // RNE
  return (unsigned short)(r >> 16);
}

__device__ __forceinline__ void gload16(const void* src, void* lds) {
  __builtin_amdgcn_global_load_lds(
      (const __attribute__((address_space(1))) unsigned*)src,
      (__attribute__((address_space(3))) unsigned*)lds, 16, 0, 0);
}

// ---------------------------------------------------------------- k_pre
__global__ __launch_bounds__(256) void k_pre(
    const float* __restrict__ w1, const float* __restrict__ w2,
    const float* __restrict__ gamma, const float* __restrict__ beta,
    const float* __restrict__ bmean, const float* __restrict__ bvar,
    const float* __restrict__ b1, const float* __restrict__ mu0,
    unsigned short* __restrict__ w1bf, unsigned short* __restrict__ w2bf,
    float* __restrict__ bnsh, f16* __restrict__ muF)
{
  int i = blockIdx.x * 256 + threadIdx.x;     // covers 1048576
  if (i < INNER_ * C_) {
    int r = i >> 8;
    float sc = gamma[r] * rsqrtf(bvar[r] + 1e-5f);
    w1bf[i] = f2bf(w1[i] * sc);
    w2bf[i] = f2bf(w2[i]);
  }
  if (i < B_ * K_ * C_) muF[i] = (f16)mu0[i & (K_ * C_ - 1)];
  if (i < INNER_) {
    float sc = gamma[i] * rsqrtf(bvar[i] + 1e-5f);
    bnsh[i] = fmaf(b1[i] - bmean[i], sc, beta[i]);
  }
}

// ---------------------------------------------------------------- k_split
__global__ __launch_bounds__(256) void k_split(const float* __restrict__ x, f16* __restrict__ xf)
{
  size_t i = (size_t)blockIdx.x * 256 + threadIdx.x;   // 2,097,152 float4s
  float4 v = ((const float4*)x)[i];
  f16x4 o; o[0] = (f16)v.x; o[1] = (f16)v.y; o[2] = (f16)v.z; o[3] = (f16)v.w;
  ((f16x4*)xf)[i] = o;
}

// ---------------------------------------------------------------- k_xT
__global__ __launch_bounds__(256) void k_xT(const float* __restrict__ x, f16* __restrict__ xTf)
{
  __shared__ float ts[64][65];
  int l0 = blockIdx.x * 64, c0 = blockIdx.y * 64, b = blockIdx.z;
  int t = threadIdx.x;
  for (int p = 0; p < 16; ++p) {
    int e = t + p * 256, i = e >> 6, j = e & 63;
    ts[i][j] = x[((size_t)b * L_ + l0 + i) * C_ + c0 + j];
  }
  __syncthreads();
  for (int p = 0; p < 16; ++p) {
    int e = t + p * 256, i = e >> 6, j = e & 63;
    xTf[((size_t)b * C_ + c0 + i) * L_ + l0 + j] = (f16)ts[j][i];
  }
}

// ---------------------------------------------------------------- k_em
// per (b, 128-row chunk): S^T = mu.x^T (MFMA) -> softmax (in-reg) -> z
// -> colsum partial -> part[k][c] += z^T.xT (MFMA, xT tile staged in LDS).
template<bool DO_MU, bool WRITE_Z>
__global__ __launch_bounds__(256) void k_em(
    const f16* __restrict__ xf,    // [B][L][C]
    const f16* __restrict__ xTf,   // [B][C][L]
    const f16* __restrict__ muF,   // [B][K][C]
    f16* __restrict__ zout,        // [B][L][K]
    float* __restrict__ cp,        // [NCH][B*K]
    f16* __restrict__ part)        // [NCH][B][K][C]
{
  __shared__ f16 mu_s[K_ * C_];    // 32KB, slot-swizzled ^(k&15)
  __shared__ f16 zT_s[K_ * RPB];   // 16KB, slot-swizzled ^(k&15)
  __shared__ f16 xtile[C_ * 128];  // 64KB [c][l], slot-swizzled ^(c&7)
  __shared__ float cpart[4][K_];

  int t = threadIdx.x, b = blockIdx.y, chn = blockIdx.x, l0 = chn * RPB;
  int w = t >> 6, lane = t & 63, l15 = lane & 15, g = lane >> 4;

  // stage mu (32KB): linear LDS dest, pre-swizzled global source (slot ^ (k&15))
#pragma unroll
  for (int q = 0; q < 8; ++q) {
    int s = q * 256 + t, k = s >> 5, sl = s & 31;
    gload16(muF + (size_t)b * (K_ * C_) + k * C_ + ((sl ^ (k & 15)) << 3), mu_s + s * 8);
  }
  if (DO_MU) {
    // stage xT tile (64KB): [c 256][l 128], source pre-swizzled (slot ^ (c&7))
#pragma unroll
    for (int q = 0; q < 16; ++q) {
      int s = q * 256 + t, c = s >> 4, sl = s & 15;
      gload16(xTf + (size_t)(b * C_ + c) * L_ + l0 + ((sl ^ (c & 7)) << 3), xtile + s * 8);
    }
    // wait for mu only (oldest 8 loads); xtile's 16 stay in flight under phase1
    asm volatile("s_waitcnt vmcnt(16)" ::: "memory");
    __builtin_amdgcn_s_barrier();
    __builtin_amdgcn_sched_barrier(0);
  } else {
    asm volatile("s_waitcnt vmcnt(0)" ::: "memory");
    __builtin_amdgcn_s_barrier();
    __builtin_amdgcn_sched_barrier(0);
  }

  // ---- phase1: S^T[k][tok]  (wave w owns tok tiles 2w, 2w+1)
  f32x4 acc[4][2];
#pragma unroll
  for (int mt = 0; mt < 4; ++mt)
#pragma unroll
    for (int n = 0; n < 2; ++n)
#pragma unroll
      for (int j = 0; j < 4; ++j) acc[mt][n][j] = 0.f;

  const f16* xr0 = xf + ((size_t)b * L_ + l0 + (w * 2 + 0) * 16 + l15) * C_ + g * 8;
  const f16* xr1 = xf + ((size_t)b * L_ + l0 + (w * 2 + 1) * 16 + l15) * C_ + g * 8;
#pragma unroll
  for (int ck = 0; ck < 8; ++ck) {
    f16x8 xb0 = *(const f16x8*)(xr0 + ck * 32);
    f16x8 xb1 = *(const f16x8*)(xr1 + ck * 32);
#pragma unroll
    for (int mt = 0; mt < 4; ++mt) {
      f16x8 a = *(const f16x8*)(mu_s + (mt * 16 + l15) * C_ + (((ck * 4 + g) ^ l15) << 3));
      acc[mt][0] = __builtin_amdgcn_mfma_f32_16x16x32_f16(a, xb0, acc[mt][0], 0, 0, 0);
      acc[mt][1] = __builtin_amdgcn_mfma_f32_16x16x32_f16(a, xb1, acc[mt][1], 0, 0, 0);
    }
  }

  // ---- phase2: softmax over k (rows); lane holds [k = mt*16+g*4+jj][tok]
  float z[4][4][2];
#pragma unroll
  for (int n = 0; n < 2; ++n) {
    float mx = acc[0][n][0];
#pragma unroll
    for (int mt = 0; mt < 4; ++mt)
#pragma unroll
      for (int jj = 0; jj < 4; ++jj) mx = fmaxf(mx, acc[mt][n][jj]);
    mx = fmaxf(mx, __shfl_xor(mx, 16, 64));
    mx = fmaxf(mx, __shfl_xor(mx, 32, 64));
    float sm = 0.f;
#pragma unroll
    for (int mt = 0; mt < 4; ++mt)
#pragma unroll
      for (int jj = 0; jj < 4; ++jj) {
        float e = __expf(acc[mt][n][jj] - mx);
        z[mt][jj][n] = e; sm += e;
      }
    sm += __shfl_xor(sm, 16, 64);
    sm += __shfl_xor(sm, 32, 64);
    float inv = 1.f / sm;
#pragma unroll
    for (int mt = 0; mt < 4; ++mt)
#pragma unroll
      for (int jj = 0; jj < 4; ++jj) z[mt][jj][n] *= inv;
  }

  // colsum over this chunk's 128 rows
#pragma unroll
  for (int mt = 0; mt < 4; ++mt)
#pragma unroll
    for (int jj = 0; jj < 4; ++jj) {
      float v = z[mt][jj][0] + z[mt][jj][1];
      v += __shfl_xor(v, 1, 64); v += __shfl_xor(v, 2, 64);
      v += __shfl_xor(v, 4, 64); v += __shfl_xor(v, 8, 64);
      if (l15 == 0) cpart[w][mt * 16 + g * 4 + jj] = v;
    }
  __syncthreads();
  if (t < K_) cp[(size_t)chn * (B_ * K_) + b * K_ + t] =
      cpart[0][t] + cpart[1][t] + cpart[2][t] + cpart[3][t];

  // write z^T to LDS (swizzled) and z to global
#pragma unroll
  for (int mt = 0; mt < 4; ++mt)
#pragma unroll
    for (int jj = 0; jj < 4; ++jj)
#pragma unroll
      for (int n = 0; n < 2; ++n) {
        int k = mt * 16 + g * 4 + jj;
        int tl = (w * 2 + n) * 16 + l15;
        f16 h = (f16)z[mt][jj][n];
        if (DO_MU)   zT_s[k * RPB + (((tl >> 3) ^ (k & 15)) << 3) + (tl & 7)] = h;
        if (WRITE_Z) zout[((size_t)b * L_ + l0 + tl) * K_ + k] = h;
      }

  // ---- phase3: part[k][c] = z^T . xT  (wave w owns c-quarter w*64)
  if (DO_MU) {
    __syncthreads();   // zT ready; also drains vmcnt(0) -> xtile landed
    f32x4 a3[4][4];
#pragma unroll
    for (int mt = 0; mt < 4; ++mt)
#pragma unroll
      for (int nt = 0; nt < 4; ++nt)
#pragma unroll
        for (int j = 0; j < 4; ++j) a3[mt][nt][j] = 0.f;
    int cb = w * 64;
#pragma unroll
    for (int ks = 0; ks < 4; ++ks) {
      f16x8 az[4], bx[4];
#pragma unroll
      for (int mt = 0; mt < 4; ++mt)
        az[mt] = *(const f16x8*)(zT_s + (mt * 16 + l15) * RPB + (((ks * 4 + g) ^ l15) << 3));
#pragma unroll
      for (int nt = 0; nt < 4; ++nt) {
        int c = cb + nt * 16 + l15;
        bx[nt] = *(const f16x8*)(xtile + c * 128 + (((ks * 4 + g) ^ (c & 7)) << 3));
      }
#pragma unroll
      for (int mt = 0; mt < 4; ++mt)
#pragma unroll
        for (int nt = 0; nt < 4; ++nt)
          a3[mt][nt] = __builtin_amdgcn_mfma_f32_16x16x32_f16(az[mt], bx[nt], a3[mt][nt], 0, 0, 0);
    }
    f16* pp = part + (((size_t)chn * B_ + b) * K_) * C_;
#pragma unroll
    for (int mt = 0; mt < 4; ++mt)
#pragma unroll
      for (int nt = 0; nt < 4; ++nt)
#pragma unroll
        for (int jj = 0; jj < 4; ++jj)
          pp[(size_t)(mt * 16 + g * 4 + jj) * C_ + cb + nt * 16 + l15] = (f16)a3[mt][nt][jj];
  }
}

// ---------------------------------------------------------------- k_mufin
template<bool LAST>
__global__ __launch_bounds__(256) void k_mufin(
    const f16* __restrict__ part, const float* __restrict__ cp,
    float* __restrict__ muB, f16* __restrict__ muF,
    float* __restrict__ zsA, float* __restrict__ outmu)
{
  int b = blockIdx.x >> 4, kg = blockIdx.x & 15, t = threadIdx.x;
  int kr = t >> 6, c4 = t & 63, k = kg * 4 + kr;
  float a0 = 0.f, a1 = 0.f, a2 = 0.f, a3 = 0.f;
#pragma unroll
  for (int chn = 0; chn < NCH; ++chn) {
    f16x4 p = *(const f16x4*)(part + (((size_t)chn * B_ + b) * K_ + k) * C_ + c4 * 4);
    a0 += (float)p[0]; a1 += (float)p[1]; a2 += (float)p[2]; a3 += (float)p[3];
  }
  float zs = 0.f;
#pragma unroll
  for (int chn = 0; chn < NCH; ++chn) zs += cp[(size_t)chn * (B_ * K_) + b * K_ + k];
  float sc = 1.f / (EPSF + zs);
  a0 *= sc; a1 *= sc; a2 *= sc; a3 *= sc;
  float ssq = a0 * a0 + a1 * a1 + a2 * a2 + a3 * a3;
#pragma unroll
  for (int off = 32; off >= 1; off >>= 1) ssq += __shfl_xor(ssq, off, 64);
  float inv = 1.f / (EPSF + sqrtf(ssq));
  a0 *= inv; a1 *= inv; a2 *= inv; a3 *= inv;
  size_t base = (size_t)(b * K_ + k) * C_ + c4 * 4;
  float4 o = make_float4(a0, a1, a2, a3);
  *(float4*)(muB + base) = o;
  f16x4 hm; hm[0] = (f16)a0; hm[1] = (f16)a1; hm[2] = (f16)a2; hm[3] = (f16)a3;
  *(f16x4*)(muF + base) = hm;
  if (c4 == 0) zsA[b * K_ + k] = zs;
  if (LAST) *(float4*)(outmu + base) = o;
}

// ---------------------------------------------------------------- k_attn
__global__ __launch_bounds__(256) void k_attn(
    const f16* __restrict__ zB, const float* __restrict__ cpB, float* __restrict__ attn)
{
  __shared__ float zt[64][68];
  __shared__ float inv_s[K_];
  int b = blockIdx.y, l0 = blockIdx.x * 64, t = threadIdx.x;
  if (t < K_) {
    float zs = 0.f;
#pragma unroll
    for (int chn = 0; chn < NCH; ++chn) zs += cpB[(size_t)chn * (B_ * K_) + b * K_ + t];
    inv_s[t] = 1.f / (EPSF + zs);
  }
  for (int p = 0; p < 16; ++p) {
    int e = t + p * 256, lo = e >> 6, k = e & 63;
    zt[lo][k] = (float)zB[((size_t)b * L_ + l0 + lo) * K_ + k];
  }
  __syncthreads();
  int lo = t & 63, kb = t >> 6;
  for (int p = 0; p < 16; ++p) {
    int k = kb * 16 + p;
    attn[((size_t)b * K_ + k) * L_ + l0 + lo] = zt[lo][k] * inv_s[k];
  }
}

// ---------------------------------------------------------------- k_recon
__global__ __launch_bounds__(256) void k_recon(
    const f16* __restrict__ zA, const float* __restrict__ zsA,
    const float* __restrict__ muB, unsigned short* __restrict__ reconbf)
{
  __shared__ float mu_s[K_ * C_];   // 64KB
  __shared__ float zn[16][68];
  __shared__ float zinv[K_];
  int b = blockIdx.y, l0 = blockIdx.x * 128, t = threadIdx.x;
  {
    const float4* msrc = (const float4*)(muB + (size_t)b * K_ * C_);
    for (int e = t; e < K_ * C_ / 4; e += 256) ((float4*)mu_s)[e] = msrc[e];
  }
  if (t < K_) zinv[t] = 1.f / (EPSF + zsA[b * K_ + t]);
  __syncthreads();
  for (int batch = 0; batch < 8; ++batch) {
    for (int e = t; e < 1024; e += 256) {
      int rr = e >> 6, k = e & 63;
      zn[rr][k] = (float)zA[((size_t)b * L_ + l0 + batch * 16 + rr) * K_ + k] * zinv[k];
    }
    __syncthreads();
    for (int rr = 0; rr < 16; ++rr) {
      float a = 0.f;
#pragma unroll
      for (int k4 = 0; k4 < 16; ++k4) {
        float4 z4 = *(const float4*)(&zn[rr][k4 * 4]);
        a = fmaf(z4.x, mu_s[(k4 * 4 + 0) * C_ + t], a);
        a = fmaf(z4.y, mu_s[(k4 * 4 + 1) * C_ + t], a);
        a = fmaf(z4.z, mu_s[(k4 * 4 + 2) * C_ + t], a);
        a = fmaf(z4.w, mu_s[(k4 * 4 + 3) * C_ + t], a);
      }
      reconbf[((size_t)b * L_ + l0 + batch * 16 + rr) * C_ + t] = f2bf(a);
    }
    __syncthreads();
  }
}

// ---------------------------------------------------------------- k_mlp
// out = relu(recon @ w1s^T + bnsh) @ w2^T + b2 ; 32x32x16 MFMA.
// 512 thr (8 waves, 2/SIMD), 128 toks/block, ICH=64, dbuf gload_lds staging.
__global__ __launch_bounds__(512, 2) void k_mlp(
    const unsigned short* __restrict__ reconbf,  // [BL][256] bf16
    const unsigned short* __restrict__ w1bf,     // [4096][256] bf16 (bn-scaled)
    const unsigned short* __restrict__ w2bf,     // [256][4096] bf16
    const float* __restrict__ bnsh, const float* __restrict__ b2,
    float* __restrict__ outr)                    // [BL][256] f32
{
  __shared__ unsigned short w1s[2][64 * 256];  // 2x32KB [i][c], slot^ (i&15)
  __shared__ unsigned short w2s[2][256 * 64];  // 2x32KB [o][i], slot^ (o&7)
  __shared__ unsigned short hs[128 * 68];      // 17KB  [tok][i], stride 68

  int t = threadIdx.x, w = t >> 6, lane = t & 63, l31 = lane & 31, l5 = lane >> 5;
  int rb = blockIdx.x * 128;
  int ih = w & 1, tt = w >> 1;     // GEMM1: i-half, tok-tile
  int ot = w;                      // GEMM2: o-tile

  // persistent recon B-frags: wave's tok-tile tt, full C=256 (16 ks)
  bf16x8 rc[16];
  const unsigned short* rrow = reconbf + (size_t)(rb + tt * 32 + l31) * C_ + l5 * 8;
#pragma unroll
  for (int ks = 0; ks < 16; ++ks) rc[ks] = *(const bf16x8*)(rrow + ks * 16);

  f32x16 acc2[4];
#pragma unroll
  for (int q = 0; q < 4; ++q)
#pragma unroll
    for (int r = 0; r < 16; ++r) acc2[q][r] = 0.f;

#define STAGE(ic, buf)                                                          \
  {                                                                             \
    _Pragma("unroll")                                                           \
    for (int q = 0; q < 4; ++q) {                                               \
      int d = q * 512 + t, i = d >> 5, sl = d & 31;                             \
      gload16(w1bf + (size_t)((ic) * 64 + i) * C_ + ((sl ^ (i & 15)) << 3),     \
              &w1s[buf][d * 8]);                                                \
    }                                                                           \
    _Pragma("unroll")                                                           \
    for (int q = 0; q < 4; ++q) {                                               \
      int d = q * 512 + t, o = d >> 3, sl = d & 7;                              \
      gload16(w2bf + (size_t)o * INNER_ + (ic) * 64 + ((sl ^ (o & 7)) << 3),    \
              &w2s[buf][d * 8]);                                                \
    }                                                                           \
  }

  STAGE(0, 0);
  __syncthreads();

  for (int ic = 0; ic < 64; ++ic) {
    int cur = ic & 1;
    if (ic < 63) STAGE(ic + 1, cur ^ 1);

    // ---- GEMM1: h[i 32][tok 32] for (ih, tt); two interleaved acc chains
    f32x16 h0, h1;
#pragma unroll
    for (int r = 0; r < 16; ++r) { h0[r] = 0.f; h1[r] = 0.f; }
    int irow = ih * 32 + l31;
#pragma unroll
    for (int ks = 0; ks < 16; ++ks) {
      bf16x8 a1 = *(const bf16x8*)(&w1s[cur][irow * 256 + (((ks * 2 + l5) ^ (l31 & 15)) << 3)]);
      if (ks & 1) h1 = __builtin_amdgcn_mfma_f32_32x32x16_bf16(a1, rc[ks], h1, 0, 0, 0);
      else        h0 = __builtin_amdgcn_mfma_f32_32x32x16_bf16(a1, rc[ks], h0, 0, 0, 0);
    }
#pragma unroll
    for (int r = 0; r < 16; ++r) h0[r] += h1[r];

    // ---- BN shift + ReLU -> hs[tok][i] (stride 68: 2-way-free b16 writes)
#pragma unroll
    for (int r = 0; r < 16; ++r) {
      int il = ih * 32 + (r & 3) + 8 * (r >> 2) + 4 * l5;
      float v = fmaxf(h0[r] + bnsh[ic * 64 + il], 0.f);
      hs[(tt * 32 + l31) * 68 + il] = f2bf(v);
    }
    // hs ready: drain LDS only — staged global_load_lds stays in flight
    asm volatile("s_waitcnt lgkmcnt(0)" ::: "memory");
    __builtin_amdgcn_s_barrier();
    __builtin_amdgcn_sched_barrier(0);

    // ---- GEMM2: wave ot owns o-tile, all 4 tok-tiles, k=64 (4 ks2)
    __builtin_amdgcn_s_setprio(1);
#pragma unroll
    for (int ks2 = 0; ks2 < 4; ++ks2) {
      bf16x8 a2 = *(const bf16x8*)(&w2s[cur][(ot * 32 + l31) * 64 + (((ks2 * 2 + l5) ^ (l31 & 7)) << 3)]);
#pragma unroll
      for (int t2 = 0; t2 < 4; ++t2) {
        bf16x8 bh = *(const bf16x8*)(&hs[(t2 * 32 + l31) * 68 + ks2 * 16 + l5 * 8]);
        acc2[t2] = __builtin_amdgcn_mfma_f32_32x32x16_bf16(a2, bh, acc2[t2], 0, 0, 0);
      }
    }
    __builtin_amdgcn_s_setprio(0);
    __syncthreads();   // drains vmcnt: next buffers staged; hs consumed
  }

  // ---- epilogue: + b2, f32x4 stores (o-consecutive quads)
#pragma unroll
  for (int t2 = 0; t2 < 4; ++t2) {
    int tok = rb + t2 * 32 + l31;
#pragma unroll
    for (int q = 0; q < 4; ++q) {
      int o = ot * 32 + q * 8 + l5 * 4;
      float4 bias = *(const float4*)(b2 + o);
      f32x4 v;
      v[0] = acc2[t2][q * 4 + 0] + bias.x;
      v[1] = acc2[t2][q * 4 + 1] + bias.y;
      v[2] = acc2[t2][q * 4 + 2] + bias.z;
      v[3] = acc2[t2][q * 4 + 3] + bias.w;
      *(f32x4*)(outr + (size_t)tok * C_ + o) = v;
    }
  }
#undef STAGE
}

// ---------------------------------------------------------------- launch
extern "C" void kernel_launch(void* const* d_in, const int* in_sizes, int n_in,
                              void* d_out, int out_size, void* d_ws, size_t ws_size,
                              hipStream_t stream)
{
  const float* x     = (const float*)d_in[0];
  const float* mu0   = (const float*)d_in[2];
  const float* w1    = (const float*)d_in[3];
  const float* b1    = (const float*)d_in[4];
  const float* gamma = (const float*)d_in[5];
  const float* beta  = (const float*)d_in[6];
  const float* bmean = (const float*)d_in[7];
  const float* bvar  = (const float*)d_in[8];
  const float* w2    = (const float*)d_in[9];
  const float* b2    = (const float*)d_in[10];
  float* out = (float*)d_out;

  char* wsb = (char*)d_ws;
  f16* part = (f16*)(wsb + 0);                                  // 8,388,608 B
  f16* zB   = part;                                             // alias (after last mufin)
  f16* zA   = (f16*)(wsb + 8388608);                            // 4,194,304
  f16* xf   = (f16*)(wsb + 12582912);                           // 16,777,216
  f16* xTf  = (f16*)(wsb + 29360128);                           // 16,777,216
  unsigned short* reconbf = (unsigned short*)(wsb + 46137344);  // 16,777,216
  unsigned short* w1bf    = (unsigned short*)(wsb + 62914560);  // 2,097,152
  unsigned short* w2bf    = (unsigned short*)(wsb + 65011712);  // 2,097,152
  f16*   muF  = (f16*)(wsb + 67108864);                         // 524,288
  float* muB  = (float*)(wsb + 67633152);                       // 1,048,576
  float* bnsh = (float*)(wsb + 68681728);                       // 16,384
  float* cpA  = (float*)(wsb + 68698112);                       // 65,536
  float* cpB  = (float*)(wsb + 68763648);                       // 65,536
  float* zsA  = (float*)(wsb + 68829184);                       // 4,096  (total ~68.8MB)

  k_pre<<<4096, 256, 0, stream>>>(w1, w2, gamma, beta, bmean, bvar, b1, mu0,
                                  w1bf, w2bf, bnsh, muF);
  k_split<<<8192, 256, 0, stream>>>(x, xf);
  k_xT<<<dim3(32, 4, 16), 256, 0, stream>>>(x, xTf);

  for (int s = 0; s < 10; ++s) {
    if (s == 9) k_em<true, true ><<<dim3(16, 16), 256, 0, stream>>>(xf, xTf, muF, zA, cpA, part);
    else        k_em<true, false><<<dim3(16, 16), 256, 0, stream>>>(xf, xTf, muF, zA, cpA, part);
    if (s == 9) k_mufin<true ><<<256, 256, 0, stream>>>(part, cpA, muB, muF, zsA, out);
    else        k_mufin<false><<<256, 256, 0, stream>>>(part, cpA, muB, muF, zsA, out);
  }
  // new_z with final mu (no mu-update; zB overlays dead part buffer)
  k_em<false, true><<<dim3(16, 16), 256, 0, stream>>>(xf, xTf, muF, zB, cpB, part);
  k_attn<<<dim3(32, 16), 256, 0, stream>>>(zB, cpB, out + 262144);
  k_recon<<<dim3(16, 16), 256, 0, stream>>>(zA, zsA, muB, reconbf);
  k_mlp<<<256, 512, 0, stream>>>(reconbf, w1bf, w2bf, bnsh, b2, out + 2359296);
}

// Round 5
// 356.567 us; speedup vs baseline: 6.2543x; 1.2589x over previous
//
#include <hip/hip_runtime.h>

constexpr int B_ = 16, L_ = 2048, C_ = 256, K_ = 64, INNER_ = 4096;
constexpr int NCH = 16;          // L-chunks
constexpr int RPB = 128;         // rows per k_em block
#define EPSF 1e-6f

typedef __attribute__((ext_vector_type(8)))  short bf16x8;
typedef __attribute__((ext_vector_type(4)))  float f32x4;
typedef __attribute__((ext_vector_type(16))) float f32x16;
typedef _Float16 f16;
typedef __attribute__((ext_vector_type(8))) _Float16 f16x8;
typedef __attribute__((ext_vector_type(4))) _Float16 f16x4;

__device__ __forceinline__ unsigned short f2bf(float f) {
  union { float f; unsigned u; } v; v.f = f;
  unsigned r = v.u + 0x7fffu + ((v.u >> 16) & 1u);   // RNE
  return (unsigned short)(r >> 16);
}

__device__ __forceinline__ void gload16(const void* src, void* lds) {
  __builtin_amdgcn_global_load_lds(
      (const __attribute__((address_space(1))) unsigned*)src,
      (__attribute__((address_space(3))) unsigned*)lds, 16, 0, 0);
}

// ---------------------------------------------------------------- k_pre
__global__ __launch_bounds__(256) void k_pre(
    const float* __restrict__ w1, const float* __restrict__ w2,
    const float* __restrict__ gamma, const float* __restrict__ beta,
    const float* __restrict__ bmean, const float* __restrict__ bvar,
    const float* __restrict__ b1, const float* __restrict__ mu0,
    unsigned short* __restrict__ w1bf, unsigned short* __restrict__ w2bf,
    f16* __restrict__ bnshH, f16* __restrict__ muF)
{
  int i = blockIdx.x * 256 + threadIdx.x;     // covers 1048576
  if (i < INNER_ * C_) {
    int r = i >> 8;
    float sc = gamma[r] * rsqrtf(bvar[r] + 1e-5f);
    w1bf[i] = f2bf(w1[i] * sc);
    w2bf[i] = f2bf(w2[i]);
  }
  if (i < B_ * K_ * C_) muF[i] = (f16)mu0[i & (K_ * C_ - 1)];
  if (i < INNER_) {
    float sc = gamma[i] * rsqrtf(bvar[i] + 1e-5f);
    bnshH[i] = (f16)fmaf(b1[i] - bmean[i], sc, beta[i]);
  }
}

// ---------------------------------------------------------------- k_xT
// x [B][L][C] f32 -> xf f16 [B][L][C] + xTf f16 [B][C][L]
__global__ __launch_bounds__(256) void k_xT(const float* __restrict__ x,
                                            f16* __restrict__ xf, f16* __restrict__ xTf)
{
  __shared__ float ts[64][65];
  int l0 = blockIdx.x * 64, c0 = blockIdx.y * 64, b = blockIdx.z;
  int t = threadIdx.x;
  for (int p = 0; p < 16; ++p) {
    int e = t + p * 256, i = e >> 6, j = e & 63;
    float vv = x[((size_t)b * L_ + l0 + i) * C_ + c0 + j];
    ts[i][j] = vv;
    xf[((size_t)b * L_ + l0 + i) * C_ + c0 + j] = (f16)vv;
  }
  __syncthreads();
  for (int p = 0; p < 16; ++p) {
    int e = t + p * 256, i = e >> 6, j = e & 63;
    xTf[((size_t)b * C_ + c0 + i) * L_ + l0 + j] = (f16)ts[j][i];
  }
}

// ---------------------------------------------------------------- k_em
// 512 thr / 8 waves (2 per SIMD). S^T = mu.x^T (MFMA) -> in-reg softmax -> z
// -> colsum partial -> part[k][c] = z^T.xT (MFMA, xtile LDS-staged async).
template<bool DO_MU, bool WRITE_Z>
__global__ __launch_bounds__(512, 2) void k_em(
    const f16* __restrict__ xf,    // [B][L][C]
    const f16* __restrict__ xTf,   // [B][C][L]
    const f16* __restrict__ muF,   // [B][K][C]
    f16* __restrict__ zout,        // [B][L][K]
    float* __restrict__ cp,        // [NCH][B*K]
    f16* __restrict__ part)        // [NCH][B][K][C]
{
  __shared__ f16 mu_s[K_ * C_];     // 32KB, slot ^ (k&15)
  __shared__ f16 zT_s[K_ * RPB];    // 16KB, slot ^ (k&15)
  __shared__ f16 xtile[C_ * RPB];   // 64KB, slot ^ (c&7)
  __shared__ float cpart[8][K_];

  int t = threadIdx.x, b = blockIdx.y, chn = blockIdx.x, l0 = chn * RPB;
  int w = t >> 6, lane = t & 63, l15 = lane & 15, g = lane >> 4;

  // stage mu (2048 slots, 4/thread) -- OLDEST vmem
#pragma unroll
  for (int q = 0; q < 4; ++q) {
    int s = q * 512 + t, k = s >> 5, sl = s & 31;
    gload16(muF + (size_t)b * (K_ * C_) + k * C_ + ((sl ^ (k & 15)) << 3), mu_s + s * 8);
  }
  __builtin_amdgcn_sched_barrier(0);
  // xf rows into regs BEFORE the xtile stage so xf waits don't drain xtile
  f16x8 xfr[8];
  const f16* xr = xf + ((size_t)b * L_ + l0 + w * 16 + l15) * C_ + g * 8;
#pragma unroll
  for (int ck = 0; ck < 8; ++ck) xfr[ck] = *(const f16x8*)(xr + ck * 32);
  __builtin_amdgcn_sched_barrier(0);
  if (DO_MU) {
    // stage xT tile (4096 slots, 8/thread) -- NEWEST, stays in flight
#pragma unroll
    for (int q = 0; q < 8; ++q) {
      int s = q * 512 + t, c = s >> 4, sl = s & 15;
      gload16(xTf + (size_t)(b * C_ + c) * L_ + l0 + ((sl ^ (c & 7)) << 3), xtile + s * 8);
    }
    __builtin_amdgcn_sched_barrier(0);
    asm volatile("s_waitcnt vmcnt(16)" ::: "memory");   // mu landed; xf+xtile in flight
  } else {
    asm volatile("s_waitcnt vmcnt(8)" ::: "memory");    // mu landed; xf in flight
  }
  __builtin_amdgcn_s_barrier();
  __builtin_amdgcn_sched_barrier(0);

  // ---- phase1: S^T[k][tok], wave w owns tok tile w
  f32x4 acc[4];
#pragma unroll
  for (int mt = 0; mt < 4; ++mt)
#pragma unroll
    for (int j = 0; j < 4; ++j) acc[mt][j] = 0.f;
#pragma unroll
  for (int ck = 0; ck < 8; ++ck) {
#pragma unroll
    for (int mt = 0; mt < 4; ++mt) {
      f16x8 a = *(const f16x8*)(mu_s + (mt * 16 + l15) * C_ + (((ck * 4 + g) ^ l15) << 3));
      acc[mt] = __builtin_amdgcn_mfma_f32_16x16x32_f16(a, xfr[ck], acc[mt], 0, 0, 0);
    }
  }

  // ---- phase2: softmax over k; lane holds k = mt*16+g*4+jj for tok = w*16+l15
  float z[4][4];
  {
    float mx = acc[0][0];
#pragma unroll
    for (int mt = 0; mt < 4; ++mt)
#pragma unroll
      for (int jj = 0; jj < 4; ++jj) mx = fmaxf(mx, acc[mt][jj]);
    mx = fmaxf(mx, __shfl_xor(mx, 16, 64));
    mx = fmaxf(mx, __shfl_xor(mx, 32, 64));
    float sm = 0.f;
#pragma unroll
    for (int mt = 0; mt < 4; ++mt)
#pragma unroll
      for (int jj = 0; jj < 4; ++jj) {
        float e = __expf(acc[mt][jj] - mx);
        z[mt][jj] = e; sm += e;
      }
    sm += __shfl_xor(sm, 16, 64);
    sm += __shfl_xor(sm, 32, 64);
    float inv = 1.f / sm;
#pragma unroll
    for (int mt = 0; mt < 4; ++mt)
#pragma unroll
      for (int jj = 0; jj < 4; ++jj) z[mt][jj] *= inv;
  }

  // colsum partial over this wave's 16 toks
#pragma unroll
  for (int mt = 0; mt < 4; ++mt)
#pragma unroll
    for (int jj = 0; jj < 4; ++jj) {
      float v = z[mt][jj];
      v += __shfl_xor(v, 1, 64); v += __shfl_xor(v, 2, 64);
      v += __shfl_xor(v, 4, 64); v += __shfl_xor(v, 8, 64);
      if (l15 == 0) cpart[w][mt * 16 + g * 4 + jj] = v;
    }

  // z -> zT LDS (swizzled) and/or z global
#pragma unroll
  for (int mt = 0; mt < 4; ++mt)
#pragma unroll
    for (int jj = 0; jj < 4; ++jj) {
      int k = mt * 16 + g * 4 + jj;
      int tl = w * 16 + l15;
      f16 h = (f16)z[mt][jj];
      if (DO_MU)   zT_s[k * RPB + (((tl >> 3) ^ (k & 15)) << 3) + (tl & 7)] = h;
      if (WRITE_Z) zout[((size_t)b * L_ + l0 + tl) * K_ + k] = h;
    }
  __syncthreads();   // zT/cpart ready; drains vmcnt -> xtile landed

  if (t < K_) {
    float s = 0.f;
#pragma unroll
    for (int q = 0; q < 8; ++q) s += cpart[q][t];
    cp[(size_t)chn * (B_ * K_) + b * K_ + t] = s;
  }

  // ---- phase3: part[k][c] = z^T . xT, wave w owns c-slice w*32..+32
  if (DO_MU) {
    f32x4 a3[4][2];
#pragma unroll
    for (int mt = 0; mt < 4; ++mt)
#pragma unroll
      for (int nt = 0; nt < 2; ++nt)
#pragma unroll
        for (int j = 0; j < 4; ++j) a3[mt][nt][j] = 0.f;
    int cb = w * 32;
#pragma unroll
    for (int ks = 0; ks < 4; ++ks) {
      f16x8 az[4], bx[2];
#pragma unroll
      for (int mt = 0; mt < 4; ++mt)
        az[mt] = *(const f16x8*)(zT_s + (mt * 16 + l15) * RPB + (((ks * 4 + g) ^ l15) << 3));
#pragma unroll
      for (int nt = 0; nt < 2; ++nt) {
        int c = cb + nt * 16 + l15;
        bx[nt] = *(const f16x8*)(xtile + c * RPB + (((ks * 4 + g) ^ (c & 7)) << 3));
      }
#pragma unroll
      for (int mt = 0; mt < 4; ++mt)
#pragma unroll
        for (int nt = 0; nt < 2; ++nt)
          a3[mt][nt] = __builtin_amdgcn_mfma_f32_16x16x32_f16(az[mt], bx[nt], a3[mt][nt], 0, 0, 0);
    }
    f16* pp = part + (((size_t)chn * B_ + b) * K_) * C_;
#pragma unroll
    for (int mt = 0; mt < 4; ++mt)
#pragma unroll
      for (int nt = 0; nt < 2; ++nt)
#pragma unroll
        for (int jj = 0; jj < 4; ++jj)
          pp[(size_t)(mt * 16 + g * 4 + jj) * C_ + cb + nt * 16 + l15] = (f16)a3[mt][nt][jj];
  }
}

// ---------------------------------------------------------------- k_mufin
template<bool LAST>
__global__ __launch_bounds__(256) void k_mufin(
    const f16* __restrict__ part, const float* __restrict__ cp,
    f16* __restrict__ muF, f16* __restrict__ muT,
    float* __restrict__ zsA, float* __restrict__ outmu)
{
  int b = blockIdx.x >> 4, kg = blockIdx.x & 15, t = threadIdx.x;
  int kr = t >> 6, c4 = t & 63, k = kg * 4 + kr;
  float a0 = 0.f, a1 = 0.f, a2 = 0.f, a3 = 0.f;
#pragma unroll
  for (int chn = 0; chn < NCH; ++chn) {
    f16x4 p = *(const f16x4*)(part + (((size_t)chn * B_ + b) * K_ + k) * C_ + c4 * 4);
    a0 += (float)p[0]; a1 += (float)p[1]; a2 += (float)p[2]; a3 += (float)p[3];
  }
  float zs = 0.f;
#pragma unroll
  for (int chn = 0; chn < NCH; ++chn) zs += cp[(size_t)chn * (B_ * K_) + b * K_ + k];
  float sc = 1.f / (EPSF + zs);
  a0 *= sc; a1 *= sc; a2 *= sc; a3 *= sc;
  float ssq = a0 * a0 + a1 * a1 + a2 * a2 + a3 * a3;
#pragma unroll
  for (int off = 32; off >= 1; off >>= 1) ssq += __shfl_xor(ssq, off, 64);
  float inv = 1.f / (EPSF + sqrtf(ssq));
  a0 *= inv; a1 *= inv; a2 *= inv; a3 *= inv;
  size_t base = (size_t)(b * K_ + k) * C_ + c4 * 4;
  f16x4 hm; hm[0] = (f16)a0; hm[1] = (f16)a1; hm[2] = (f16)a2; hm[3] = (f16)a3;
  *(f16x4*)(muF + base) = hm;
  if (c4 == 0) zsA[b * K_ + k] = zs;
  if (LAST) {
    *(float4*)(outmu + base) = make_float4(a0, a1, a2, a3);
    muT[((size_t)b * C_ + c4 * 4 + 0) * K_ + k] = hm[0];   // mu^T for k_mlp recon
    muT[((size_t)b * C_ + c4 * 4 + 1) * K_ + k] = hm[1];
    muT[((size_t)b * C_ + c4 * 4 + 2) * K_ + k] = hm[2];
    muT[((size_t)b * C_ + c4 * 4 + 3) * K_ + k] = hm[3];
  }
}

// ---------------------------------------------------------------- k_attn
__global__ __launch_bounds__(256) void k_attn(
    const f16* __restrict__ zB, const float* __restrict__ cpB, float* __restrict__ attn)
{
  __shared__ float zt[64][68];
  __shared__ float inv_s[K_];
  int b = blockIdx.y, l0 = blockIdx.x * 64, t = threadIdx.x;
  if (t < K_) {
    float zs = 0.f;
#pragma unroll
    for (int chn = 0; chn < NCH; ++chn) zs += cpB[(size_t)chn * (B_ * K_) + b * K_ + t];
    inv_s[t] = 1.f / (EPSF + zs);
  }
  for (int p = 0; p < 16; ++p) {
    int e = t + p * 256, lo = e >> 6, k = e & 63;
    zt[lo][k] = (float)zB[((size_t)b * L_ + l0 + lo) * K_ + k];
  }
  __syncthreads();
  int lo = t & 63, kb = t >> 6;
  for (int p = 0; p < 16; ++p) {
    int k = kb * 16 + p;
    attn[((size_t)b * K_ + k) * L_ + l0 + lo] = zt[lo][k] * inv_s[k];
  }
}

// ---------------------------------------------------------------- k_mlp
// prologue: recon = (z*zinv) @ mu via MFMA, written into B-frag layout in LDS.
// main loop: out = relu(recon @ w1s^T + bnsh) @ w2^T + b2, counted-vmcnt pipeline.
__global__ __launch_bounds__(512, 2) void k_mlp(
    const f16* __restrict__ zA,                  // [BL][64]
    const f16* __restrict__ muT,                 // [B][C][K]
    const float* __restrict__ zsA,               // [B][K]
    const unsigned short* __restrict__ w1bf,     // [4096][256] bf16 (bn-scaled)
    const unsigned short* __restrict__ w2bf,     // [256][4096] bf16
    const f16* __restrict__ bnshH, const float* __restrict__ b2,
    float* __restrict__ outr)                    // [BL][256] f32
{
  __shared__ unsigned short w1s[2][64 * 256];  // 64KB; prologue: rcs_frag
  __shared__ unsigned short w2s[2][256 * 64];  // 64KB; prologue: muT_s + z_s
  __shared__ unsigned short hs[128 * 68];      // 17KB [tok][i]
  __shared__ f16 bns_s[INNER_];                // 8KB
  __shared__ float zinv_s[K_];

  int t = threadIdx.x, w = t >> 6, lane = t & 63, l31 = lane & 31, l5 = lane >> 5;
  int rb = blockIdx.x * 128, b = rb >> 11, l0 = rb & 2047;
  int tt = w >> 1, ih = w & 1;   // GEMM1: tok-tile, i-half ; GEMM2: o-tile = w

  f16* muT_s = (f16*)w2s[0];              // [c 256][8 slots], slot ^ (c&7)
  f16* z_s   = (f16*)w2s[1];              // [tok 128][8 slots], slot ^ (tok&7)
  unsigned short* rcs = w1s[0];           // frag layout [tile4][ks16][lane64][8]

  // ---- prologue staging
  if (t < K_) zinv_s[t] = 1.f / (EPSF + zsA[b * K_ + t]);
#pragma unroll
  for (int q = 0; q < 4; ++q) {
    int s = q * 512 + t, c = s >> 3, sl = s & 7;
    gload16(muT + ((size_t)b * C_ + c) * K_ + ((sl ^ (c & 7)) << 3), muT_s + s * 8);
  }
#pragma unroll
  for (int q = 0; q < 2; ++q) {
    int s = q * 512 + t, tok = s >> 3, sl = s & 7;
    gload16(zA + ((size_t)b * L_ + l0 + tok) * K_ + ((sl ^ (tok & 7)) << 3), z_s + s * 8);
  }
  gload16(bnshH + t * 8, bns_s + t * 8);
  asm volatile("s_waitcnt vmcnt(0) lgkmcnt(0)" ::: "memory");
  __builtin_amdgcn_s_barrier();
  __builtin_amdgcn_sched_barrier(0);

  // ---- recon MFMA: D[c 32][tok 32] per (tt, ch=ih); K = 64
  {
    f16x8 bz[4];
#pragma unroll
    for (int kk = 0; kk < 4; ++kk) {
      int tok = tt * 32 + l31;
      f16x8 zr = *(const f16x8*)(z_s + tok * 64 + (((kk * 2 + l5) ^ (tok & 7)) << 3));
      f16x8 sc;
#pragma unroll
      for (int e = 0; e < 8; ++e)
        sc[e] = (f16)((float)zr[e] * zinv_s[kk * 16 + l5 * 8 + e]);
      bz[kk] = sc;
    }
    f32x16 d0, d1, d2, d3;
#pragma unroll
    for (int r = 0; r < 16; ++r) { d0[r] = 0.f; d1[r] = 0.f; d2[r] = 0.f; d3[r] = 0.f; }
#pragma unroll
    for (int kk = 0; kk < 4; ++kk) {
#pragma unroll
      for (int m = 0; m < 4; ++m) {
        int c = ih * 128 + m * 32 + l31;
        f16x8 am = *(const f16x8*)(muT_s + c * 64 + (((kk * 2 + l5) ^ (c & 7)) << 3));
        if (m == 0) d0 = __builtin_amdgcn_mfma_f32_32x32x16_f16(am, bz[kk], d0, 0, 0, 0);
        if (m == 1) d1 = __builtin_amdgcn_mfma_f32_32x32x16_f16(am, bz[kk], d1, 0, 0, 0);
        if (m == 2) d2 = __builtin_amdgcn_mfma_f32_32x32x16_f16(am, bz[kk], d2, 0, 0, 0);
        if (m == 3) d3 = __builtin_amdgcn_mfma_f32_32x32x16_f16(am, bz[kk], d3, 0, 0, 0);
      }
    }
    asm volatile("s_waitcnt lgkmcnt(0)" ::: "memory");
    __builtin_amdgcn_s_barrier();      // all muT_s/z_s reads done -> w2s reusable;
    __builtin_amdgcn_sched_barrier(0); // also orders rcs writes below vs other waves
    // scatter D into B-frag layout: rc[ks][j] = recon[tok=l31][c=ks*16+l5*8+j]
#pragma unroll
    for (int m = 0; m < 4; ++m) {
#pragma unroll
      for (int r = 0; r < 16; ++r) {
        int c = ih * 128 + m * 32 + (r & 3) + 8 * (r >> 2) + 4 * l5;
        int ks = c >> 4, l5p = (c >> 3) & 1, j = c & 7;
        float val = (m == 0) ? d0[r] : (m == 1) ? d1[r] : (m == 2) ? d2[r] : d3[r];
        rcs[(((tt * 16 + ks) * 64) + l5p * 32 + l31) * 8 + j] = f2bf(val);
      }
    }
  }
  asm volatile("s_waitcnt lgkmcnt(0)" ::: "memory");
  __builtin_amdgcn_s_barrier();
  __builtin_amdgcn_sched_barrier(0);

  // persistent recon B-frags for this wave's tok-tile
  bf16x8 rc[16];
#pragma unroll
  for (int ks = 0; ks < 16; ++ks)
    rc[ks] = *(const bf16x8*)(rcs + ((tt * 16 + ks) * 64 + lane) * 8);
  asm volatile("s_waitcnt lgkmcnt(0)" ::: "memory");
  __builtin_amdgcn_s_barrier();      // rc in regs -> w1s reusable for staging
  __builtin_amdgcn_sched_barrier(0);

  f32x16 acc2[4];
#pragma unroll
  for (int q = 0; q < 4; ++q)
#pragma unroll
    for (int r = 0; r < 16; ++r) acc2[q][r] = 0.f;

#define STAGE(ic, buf)                                                          \
  {                                                                             \
    _Pragma("unroll")                                                           \
    for (int q = 0; q < 4; ++q) {                                               \
      int d = q * 512 + t, i = d >> 5, sl = d & 31;                             \
      gload16(w1bf + (size_t)((ic) * 64 + i) * C_ + ((sl ^ (i & 15)) << 3),     \
              &w1s[buf][d * 8]);                                                \
    }                                                                           \
    _Pragma("unroll")                                                           \
    for (int q = 0; q < 4; ++q) {                                               \
      int d = q * 512 + t, o = d >> 3, sl = d & 7;                              \
      gload16(w2bf + (size_t)o * INNER_ + (ic) * 64 + ((sl ^ (o & 7)) << 3),    \
              &w2s[buf][d * 8]);                                                \
    }                                                                           \
  }

  STAGE(0, 0);
  for (int ic = 0; ic < 64; ++ic) {
    int cur = ic & 1;
    __builtin_amdgcn_sched_barrier(0);
    if (ic < 63) STAGE(ic + 1, cur ^ 1);
    __builtin_amdgcn_sched_barrier(0);
    if (ic < 63) { asm volatile("s_waitcnt vmcnt(8)" ::: "memory"); }  // STAGE(ic) landed
    else         { asm volatile("s_waitcnt vmcnt(0)" ::: "memory"); }
    __builtin_amdgcn_s_barrier();
    __builtin_amdgcn_sched_barrier(0);

    // ---- GEMM1: h[i 32][tok 32] for (ih, tt)
    f32x16 h0, h1;
#pragma unroll
    for (int r = 0; r < 16; ++r) { h0[r] = 0.f; h1[r] = 0.f; }
    int irow = ih * 32 + l31;
#pragma unroll
    for (int ks = 0; ks < 16; ++ks) {
      bf16x8 a1 = *(const bf16x8*)(&w1s[cur][irow * 256 + (((ks * 2 + l5) ^ (irow & 15)) << 3)]);
      if (ks & 1) h1 = __builtin_amdgcn_mfma_f32_32x32x16_bf16(a1, rc[ks], h1, 0, 0, 0);
      else        h0 = __builtin_amdgcn_mfma_f32_32x32x16_bf16(a1, rc[ks], h0, 0, 0, 0);
    }
#pragma unroll
    for (int r = 0; r < 16; ++r) h0[r] += h1[r];

    // ---- BN shift (LDS) + ReLU -> hs, packed b32 stores
#pragma unroll
    for (int rp = 0; rp < 8; ++rp) {
      int r0 = rp * 2;
      int il = ih * 32 + 2 * (rp & 1) + 8 * (rp >> 1) + 4 * l5;
      float v0 = fmaxf(h0[r0]     + (float)bns_s[ic * 64 + il],     0.f);
      float v1 = fmaxf(h0[r0 + 1] + (float)bns_s[ic * 64 + il + 1], 0.f);
      unsigned u = (unsigned)f2bf(v0) | ((unsigned)f2bf(v1) << 16);
      *(unsigned*)(hs + (tt * 32 + l31) * 68 + il) = u;
    }
    asm volatile("s_waitcnt lgkmcnt(0)" ::: "memory");   // hs visible; vmem stays in flight
    __builtin_amdgcn_s_barrier();
    __builtin_amdgcn_sched_barrier(0);

    // ---- GEMM2: wave w owns o-tile, all 4 tok-tiles, k=64
    __builtin_amdgcn_s_setprio(1);
#pragma unroll
    for (int ks2 = 0; ks2 < 4; ++ks2) {
      int orow = w * 32 + l31;
      bf16x8 a2 = *(const bf16x8*)(&w2s[cur][orow * 64 + (((ks2 * 2 + l5) ^ (orow & 7)) << 3)]);
#pragma unroll
      for (int t2 = 0; t2 < 4; ++t2) {
        bf16x8 bh = *(const bf16x8*)(&hs[(t2 * 32 + l31) * 68 + ks2 * 16 + l5 * 8]);
        acc2[t2] = __builtin_amdgcn_mfma_f32_32x32x16_bf16(a2, bh, acc2[t2], 0, 0, 0);
      }
    }
    __builtin_amdgcn_s_setprio(0);
    asm volatile("s_waitcnt lgkmcnt(0)" ::: "memory");   // LDS reads done; NO vmcnt drain
    __builtin_amdgcn_s_barrier();
    __builtin_amdgcn_sched_barrier(0);
  }
#undef STAGE

  // ---- epilogue: + b2, f32x4 stores
#pragma unroll
  for (int t2 = 0; t2 < 4; ++t2) {
    int tok = rb + t2 * 32 + l31;
#pragma unroll
    for (int q = 0; q < 4; ++q) {
      int o = w * 32 + q * 8 + l5 * 4;
      float4 bias = *(const float4*)(b2 + o);
      f32x4 v;
      v[0] = acc2[t2][q * 4 + 0] + bias.x;
      v[1] = acc2[t2][q * 4 + 1] + bias.y;
      v[2] = acc2[t2][q * 4 + 2] + bias.z;
      v[3] = acc2[t2][q * 4 + 3] + bias.w;
      *(f32x4*)(outr + (size_t)tok * C_ + o) = v;
    }
  }
}

// ---------------------------------------------------------------- launch
extern "C" void kernel_launch(void* const* d_in, const int* in_sizes, int n_in,
                              void* d_out, int out_size, void* d_ws, size_t ws_size,
                              hipStream_t stream)
{
  const float* x     = (const float*)d_in[0];
  const float* mu0   = (const float*)d_in[2];
  const float* w1    = (const float*)d_in[3];
  const float* b1    = (const float*)d_in[4];
  const float* gamma = (const float*)d_in[5];
  const float* beta  = (const float*)d_in[6];
  const float* bmean = (const float*)d_in[7];
  const float* bvar  = (const float*)d_in[8];
  const float* w2    = (const float*)d_in[9];
  const float* b2    = (const float*)d_in[10];
  float* out = (float*)d_out;

  char* wsb = (char*)d_ws;
  f16* part = (f16*)(wsb + 0);                                  // 8,388,608 B
  f16* zB   = part;                                             // alias (dead after last mufin)
  f16* zA   = (f16*)(wsb + 8388608);                            // 4,194,304
  f16* xf   = (f16*)(wsb + 12582912);                           // 16,777,216
  f16* xTf  = (f16*)(wsb + 29360128);                           // 16,777,216
  unsigned short* w1bf = (unsigned short*)(wsb + 46137344);     // 2,097,152
  unsigned short* w2bf = (unsigned short*)(wsb + 48234496);     // 2,097,152
  f16*   muF   = (f16*)(wsb + 50331648);                        // 524,288
  f16*   muT   = (f16*)(wsb + 50855936);                        // 524,288
  f16*   bnshH = (f16*)(wsb + 51380224);                        // 8,192
  float* cpA   = (float*)(wsb + 51388416);                      // 65,536
  float* cpB   = (float*)(wsb + 51453952);                      // 65,536
  float* zsA   = (float*)(wsb + 51519488);                      // 4,096  (~51.5MB)

  k_pre<<<4096, 256, 0, stream>>>(w1, w2, gamma, beta, bmean, bvar, b1, mu0,
                                  w1bf, w2bf, bnshH, muF);
  k_xT<<<dim3(32, 4, 16), 256, 0, stream>>>(x, xf, xTf);

  for (int s = 0; s < 10; ++s) {
    if (s == 9) k_em<true, true ><<<dim3(16, 16), 512, 0, stream>>>(xf, xTf, muF, zA, cpA, part);
    else        k_em<true, false><<<dim3(16, 16), 512, 0, stream>>>(xf, xTf, muF, zA, cpA, part);
    if (s == 9) k_mufin<true ><<<256, 256, 0, stream>>>(part, cpA, muF, muT, zsA, out);
    else        k_mufin<false><<<256, 256, 0, stream>>>(part, cpA, muF, muT, zsA, out);
  }
  // new_z with final mu (no mu-update; zB overlays dead part buffer)
  k_em<false, true><<<dim3(16, 16), 512, 0, stream>>>(xf, xTf, muF, zB, cpB, part);
  k_attn<<<dim3(32, 16), 256, 0, stream>>>(zB, cpB, out + 262144);
  k_mlp<<<256, 512, 0, stream>>>(zA, muT, zsA, w1bf, w2bf, bnshH, b2, out + 2359296);
}